// Round 4
// baseline (915.868 us; speedup 1.0000x reference)
//
#include <hip/hip_runtime.h>
#include <cstdint>

#define DEV __device__ __forceinline__

typedef __attribute__((ext_vector_type(8))) short bf16x8;
typedef __attribute__((ext_vector_type(4))) float f32x4;
typedef unsigned short u16;
typedef unsigned int   u32;

// ---------- bf16 helpers (manual RNE) ----------
DEV u16 f2bf(float f) {
  u32 u = __float_as_uint(f);
  u = (u + 0x7FFFu + ((u >> 16) & 1u)) >> 16;
  return (u16)u;
}
DEV float bf2f(u16 s) { return __uint_as_float(((u32)s) << 16); }

DEV float gelu_f(float x) { return 0.5f * x * (1.f + erff(x * 0.70710678118654752f)); }

// ---------- async global->LDS (16B per lane) ----------
DEV void gload_lds16(const void* g, void* l) {
  typedef __attribute__((address_space(1))) const unsigned int GU;
  typedef __attribute__((address_space(3))) unsigned int LU;
  __builtin_amdgcn_global_load_lds((GU*)(uintptr_t)g, (LU*)(u32)(uintptr_t)l, 16, 0, 0);
}

// LDS byte swizzle: XOR 16B-slot bits (4-6) with row bits (7-9). Involution,
// spreads 8 consecutive 128B rows across all 8 16B slots -> 2-way max (free).
DEV int swz(int x) { return x ^ (((x >> 7) & 7) << 4); }

// packed causal score layout: per batch, 136 lower-triangle 128x128 tiles,
// tile (mt,nt) nt<=mt at (mt*(mt+1)/2 + nt)*16384, row-major inside.
#define BATCH_SC 2228224L   // u16 elements per batch (136*16384)

// MODE epilogue shared by both 256-tile kernels:
// MODE 0: QKV fused   -> bf16, +bias (bq/bk/bv routed by gc>>10)
// MODE 3: FFN1 half   -> bf16, +bias, gelu
// MODE 4: FFN2 pass 0 -> f32 raw partial
// MODE 5: FFN2 pass 1 -> f32 += partial + bias + resid(bf16)
#define EPILOGUE_256()                                                                 \
  _Pragma("unroll")                                                                    \
  for (int mi = 0; mi < 8; ++mi) {                                                     \
    _Pragma("unroll")                                                                  \
    for (int ni = 0; ni < 4; ++ni) {                                                   \
      const int gc = n0 + wn * 64 + ni * 16 + lrow;                                    \
      _Pragma("unroll")                                                                \
      for (int e = 0; e < 4; ++e) {                                                    \
        const int gr = m0 + wm * 128 + mi * 16 + kgrp * 4 + e;                         \
        const float v = acc[mi][ni][e];                                                \
        if (MODE == 0) {                                                               \
          const float bval = gc < 1024 ? bias[gc]                                      \
                              : (gc < 2048 ? bias2[gc & 1023] : bias3[gc & 1023]);     \
          ((u16*)Cv)[(long)(gc >> 10) * 16777216 + (long)gr * 1024 + (gc & 1023)]      \
              = f2bf(v + bval);                                                        \
        } else if (MODE == 3) {                                                        \
          ((u16*)Cv)[(long)gr * ldc + gc] = f2bf(gelu_f(v + bias[gc]));                \
        } else if (MODE == 4) {                                                        \
          ((float*)Cv)[(long)gr * ldc + gc] = v;                                       \
        } else {                                                                       \
          float* o = (float*)Cv + (long)gr * ldc + gc;                                 \
          *o = *o + v + bias[gc] + bf2f(resid[(long)gr * 1024 + gc]);                  \
        }                                                                              \
      }                                                                                \
    }                                                                                  \
  }

// Common setup for 256x256-tile kernels: T1 bijective XCD swizzle + M-major
// tile order (consecutive blocks share the A panel -> L2 reuse).
#define SETUP_256()                                                                    \
  __shared__ char smem[131072];                                                        \
  const int tid  = threadIdx.x;                                                        \
  const int lane = tid & 63;                                                           \
  const int wv   = tid >> 6;                                                           \
  const int wm   = wv >> 2, wn = wv & 3;                                               \
  const int lrow = lane & 15;                                                          \
  const int kgrp = lane >> 4;                                                          \
  const int nwg = gridDim.x;                                                           \
  const int q0 = nwg >> 3, r = nwg & 7, xc = blockIdx.x & 7, pos = blockIdx.x >> 3;    \
  const int s = (xc < r ? xc * (q0 + 1) : r * (q0 + 1) + (xc - r) * q0) + pos;         \
  const int mt = s / NNT, nt = s % NNT;                                                \
  const int m0 = mt * 256, n0 = nt * 256;                                              \
  auto stageA = [&](int ktile, int dslot, int h) {                                     \
    int k0 = ktile << 6; const int kmax = K - 64; if (k0 > kmax) k0 = kmax;            \
    _Pragma("unroll")                                                                  \
    for (int j = 0; j < 2; ++j) {                                                      \
      const int o = j * 8192 + tid * 16;                                               \
      const int l = swz(o);                                                            \
      gload_lds16(A + (long)(m0 + h * 128 + (l >> 7)) * lda + k0 + ((l & 127) >> 1),   \
                  smem + dslot * 65536 + h * 16384 + o);                               \
    }                                                                                  \
  };                                                                                   \
  auto stageB = [&](int ktile, int dslot, int h) {                                     \
    int k0 = ktile << 6; const int kmax = K - 64; if (k0 > kmax) k0 = kmax;            \
    _Pragma("unroll")                                                                  \
    for (int j = 0; j < 2; ++j) {                                                      \
      const int o = j * 8192 + tid * 16;                                               \
      const int l = swz(o);                                                            \
      gload_lds16(Bt + (long)(n0 + h * 128 + (l >> 7)) * ldb + k0 + ((l & 127) >> 1),  \
                  smem + dslot * 65536 + 32768 + h * 16384 + o);                       \
    }                                                                                  \
  };                                                                                   \
  auto rdfrag = [&](int bofs, int row, int ks) -> bf16x8 {                             \
    const int p = swz(row * 128 + ks * 64 + kgrp * 16);                                \
    return *(const bf16x8*)(smem + bofs + p);                                          \
  };                                                                                   \
  f32x4 acc[8][4];                                                                     \
  _Pragma("unroll")                                                                    \
  for (int mi = 0; mi < 8; ++mi)                                                       \
    _Pragma("unroll")                                                                  \
    for (int ni = 0; ni < 4; ++ni)                                                     \
      _Pragma("unroll")                                                                \
      for (int e = 0; e < 4; ++e) acc[mi][ni][e] = 0.f;

// =====================================================================
// gemm256_p8: 8-phase counted-vmcnt pipeline (T1+T2+T3+T4+T5)
// =====================================================================
template<int MODE>
__global__ __launch_bounds__(512, 2)
void gemm256_p8(const u16* __restrict__ A, int lda,
                const u16* __restrict__ Bt, int ldb,
                void* __restrict__ Cv, int ldc,
                const float* __restrict__ bias,
                const float* __restrict__ bias2,
                const float* __restrict__ bias3,
                const u16* __restrict__ resid,
                int K, int NNT)
{
  SETUP_256();

  // prologue: slot0 <- K-tile 0 (all 4 halves), slot1 <- B of K-tile 1
  stageA(0, 0, 0); stageA(0, 0, 1); stageB(0, 0, 0); stageB(0, 0, 1);
  stageB(1, 1, 0); stageB(1, 1, 1);
  asm volatile("s_waitcnt vmcnt(4)" ::: "memory");  // K-tile 0 resident
  __builtin_amdgcn_s_barrier();

  const int NI = K >> 7;   // 2 K-tiles per iteration (K % 128 == 0)
  bf16x8 bfrag[4][2], afrag[2][2];
  for (int i = 0; i < NI; ++i) {
    const int kp = 2 * i;
#pragma unroll
    for (int d = 0; d < 2; ++d) {
#pragma unroll
      for (int mq = 0; mq < 4; ++mq) {
        const int ph = d * 4 + mq;
        if (mq == 0) {
#pragma unroll
          for (int ni = 0; ni < 4; ++ni)
#pragma unroll
            for (int ks = 0; ks < 2; ++ks)
              bfrag[ni][ks] = rdfrag(d * 65536 + 32768, wn * 64 + ni * 16 + lrow, ks);
        }
#pragma unroll
        for (int mi2 = 0; mi2 < 2; ++mi2)
#pragma unroll
          for (int ks = 0; ks < 2; ++ks)
            afrag[mi2][ks] = rdfrag(d * 65536, wm * 128 + (2 * mq + mi2) * 16 + lrow, ks);
        // one half-tile prefetch per phase (race-free by barrier separation;
        // resident-guarantee via vmcnt(4) at mq==3)
        switch (ph) {
          case 0: stageA(kp + 1, 1, 0); break;
          case 1: stageA(kp + 1, 1, 1); break;
          case 2: stageB(kp + 2, 0, 0); break;
          case 3: stageB(kp + 2, 0, 1); break;
          case 4: stageA(kp + 2, 0, 0); break;
          case 5: stageA(kp + 2, 0, 1); break;
          case 6: stageB(kp + 3, 1, 0); break;
          case 7: stageB(kp + 3, 1, 1); break;
        }
        __builtin_amdgcn_s_barrier();
        asm volatile("s_waitcnt lgkmcnt(0)" ::: "memory");
        __builtin_amdgcn_s_setprio(1);
#pragma unroll
        for (int mi2 = 0; mi2 < 2; ++mi2)
#pragma unroll
          for (int ni = 0; ni < 4; ++ni)
#pragma unroll
            for (int ks = 0; ks < 2; ++ks)
              acc[2 * mq + mi2][ni] = __builtin_amdgcn_mfma_f32_16x16x32_bf16(
                  afrag[mi2][ks], bfrag[ni][ks], acc[2 * mq + mi2][ni], 0, 0, 0);
        __builtin_amdgcn_s_setprio(0);
        if (mq == 3) asm volatile("s_waitcnt vmcnt(4)" ::: "memory");
        __builtin_amdgcn_s_barrier();
      }
    }
  }
  EPILOGUE_256();
}

// =====================================================================
// gemm256_p2: minimal 2-phase double-buffer (T3-minimum recipe, m230-V0)
// =====================================================================
template<int MODE>
__global__ __launch_bounds__(512, 2)
void gemm256_p2(const u16* __restrict__ A, int lda,
                const u16* __restrict__ Bt, int ldb,
                void* __restrict__ Cv, int ldc,
                const float* __restrict__ bias,
                const float* __restrict__ bias2,
                const float* __restrict__ bias3,
                const u16* __restrict__ resid,
                int K, int NNT)
{
  SETUP_256();

  auto stageAll = [&](int kt, int slot) {
    stageA(kt, slot, 0); stageA(kt, slot, 1);
    stageB(kt, slot, 0); stageB(kt, slot, 1);
  };

  stageAll(0, 0);
  __syncthreads();                    // vmcnt(0) + barrier
  const int NT = K >> 6;
  for (int kt = 0; kt < NT; ++kt) {
    const int cur = kt & 1;
    if (kt + 1 < NT) stageAll(kt + 1, cur ^ 1);   // issue next-tile loads FIRST
    bf16x8 bfr[4][2];
#pragma unroll
    for (int ni = 0; ni < 4; ++ni)
#pragma unroll
      for (int ks = 0; ks < 2; ++ks)
        bfr[ni][ks] = rdfrag(cur * 65536 + 32768, wn * 64 + ni * 16 + lrow, ks);
#pragma unroll
    for (int mi = 0; mi < 8; ++mi) {
      bf16x8 af[2];
#pragma unroll
      for (int ks = 0; ks < 2; ++ks)
        af[ks] = rdfrag(cur * 65536, wm * 128 + mi * 16 + lrow, ks);
#pragma unroll
      for (int ni = 0; ni < 4; ++ni)
#pragma unroll
        for (int ks = 0; ks < 2; ++ks)
          acc[mi][ni] = __builtin_amdgcn_mfma_f32_16x16x32_bf16(
              af[ks], bfr[ni][ks], acc[mi][ni], 0, 0, 0);
    }
    __syncthreads();                  // drains vmcnt+lgkm, flips buffer
  }
  EPILOGUE_256();
}

// =====================================================================
// gemm_bt 128x128 (proven m97 structure) for attention GEMMs, grid.z=batch
// MODE 1: scores = q@k^T*scale -> packed causal bf16 tiles
// MODE 2: attn = probs(packed)@vt^T -> f32 (d_out), Keff=(mt+1)*128
// =====================================================================
template<int MODE>
__global__ __launch_bounds__(256, 2)
void gemm_bt(const u16* __restrict__ A, int lda, long abst,
             const u16* __restrict__ Bt, int ldb, long bbst,
             void* __restrict__ Cv, int ldc, long cbst,
             int K, float scale)
{
  const int nt = blockIdx.x, mt = blockIdx.y, bz = blockIdx.z;
  if (MODE == 1 && nt > mt) return;
  const int Keff = (MODE == 2) ? (mt + 1) * 128 : K;

  __shared__ u16 As[128 * 64];
  __shared__ u16 Bs[128 * 64];

  const int tid  = threadIdx.x;
  const int lane = tid & 63;
  const int wv   = tid >> 6;
  const int wr   = wv >> 1, wc = wv & 1;
  const int lrow = lane & 15;
  const int kgrp = lane >> 4;
  const int m0 = mt * 128, n0 = nt * 128;

  const int srow = tid >> 3;
  const int scol = (tid & 7) * 8;
  const u16* Ag;
  if (MODE == 2) {  // packed probs: chunk (k0>>7) at tri-offset, row stride 128
    Ag = A + bz * BATCH_SC + (long)(mt * (mt + 1) / 2) * 16384 + srow * 128 + scol;
  } else {
    Ag = A + (long)bz * abst + (long)(m0 + srow) * lda + scol;
  }
  const u16* Bg = Bt + (long)bz * bbst + (long)(n0 + srow) * ldb + scol;
  char* AsW = (char*)As + wv * 1024;
  char* BsW = (char*)Bs + wv * 1024;

  f32x4 acc[4][4];
#pragma unroll
  for (int mi = 0; mi < 4; ++mi)
#pragma unroll
    for (int ni = 0; ni < 4; ++ni)
#pragma unroll
      for (int e = 0; e < 4; ++e) acc[mi][ni][e] = 0.f;

  for (int k0 = 0; k0 < Keff; k0 += 64) {
#pragma unroll
    for (int i = 0; i < 4; ++i) {
      if (MODE == 2)
        gload_lds16(Ag + (long)(k0 >> 7) * 16384 + (k0 & 127) + i * 32 * 128, AsW + i * 4096);
      else
        gload_lds16(Ag + k0 + (long)i * 32 * lda, AsW + i * 4096);
      gload_lds16(Bg + k0 + (long)i * 32 * ldb, BsW + i * 4096);
    }
    __syncthreads();
#pragma unroll
    for (int kk = 0; kk < 2; ++kk) {
      const int kof = kk * 32 + kgrp * 8;
      bf16x8 af[4], bfr[4];
#pragma unroll
      for (int mi = 0; mi < 4; ++mi)
        af[mi] = *(const bf16x8*)&As[(wr * 64 + mi * 16 + lrow) * 64 + kof];
#pragma unroll
      for (int ni = 0; ni < 4; ++ni)
        bfr[ni] = *(const bf16x8*)&Bs[(wc * 64 + ni * 16 + lrow) * 64 + kof];
#pragma unroll
      for (int mi = 0; mi < 4; ++mi)
#pragma unroll
        for (int ni = 0; ni < 4; ++ni)
          acc[mi][ni] = __builtin_amdgcn_mfma_f32_16x16x32_bf16(af[mi], bfr[ni], acc[mi][ni], 0, 0, 0);
    }
    __syncthreads();
  }

#pragma unroll
  for (int mi = 0; mi < 4; ++mi) {
#pragma unroll
    for (int ni = 0; ni < 4; ++ni) {
#pragma unroll
      for (int e = 0; e < 4; ++e) {
        const int rr = wr * 64 + mi * 16 + kgrp * 4 + e;   // row in tile
        const int cc = wc * 64 + ni * 16 + lrow;           // col in tile
        const float v = acc[mi][ni][e];
        if (MODE == 1) {
          ((u16*)Cv)[bz * BATCH_SC + (long)(mt * (mt + 1) / 2 + nt) * 16384 + rr * 128 + cc]
              = f2bf(v * scale);
        } else {
          ((float*)Cv)[(long)bz * cbst + (long)(m0 + rr) * ldc + n0 + cc] = v;
        }
      }
    }
  }
}

// ---------- transpose (+convert) to bf16 [C][R]; INBF: 0=f32, 1=bf16 ----------
template<int INBF>
__global__ __launch_bounds__(256)
void transpose_bf16(const void* __restrict__ inv, u16* __restrict__ out,
                    int R, int C, long ibst, long obst)
{
  __shared__ float t[32][33];
  const int bz = blockIdx.z;
  const int c0 = blockIdx.x * 32, r0 = blockIdx.y * 32;
  const int tx = threadIdx.x & 31, ty = threadIdx.x >> 5;
#pragma unroll
  for (int i = 0; i < 32; i += 8) {
    const long idx = (long)bz * ibst + (long)(r0 + ty + i) * C + (c0 + tx);
    t[ty + i][tx] = INBF ? bf2f(((const u16*)inv)[idx]) : ((const float*)inv)[idx];
  }
  __syncthreads();
#pragma unroll
  for (int i = 0; i < 32; i += 8)
    out[(long)bz * obst + (long)(c0 + ty + i) * R + (r0 + tx)] = f2bf(t[tx][ty + i]);
}

// ---------- f32 -> bf16 convert ----------
__global__ __launch_bounds__(256)
void cvt_f32_to_bf16(const float* __restrict__ in, u16* __restrict__ out, long n)
{
  const long idx = ((long)blockIdx.x * 256 + threadIdx.x) * 4;
  if (idx >= n) return;
  const float4 v = *(const float4*)(in + idx);
  ushort4 o;
  o.x = f2bf(v.x); o.y = f2bf(v.y); o.z = f2bf(v.z); o.w = f2bf(v.w);
  *(ushort4*)(out + idx) = o;
}

// ---------- causal row softmax on packed bf16 tiles, in place ----------
__global__ __launch_bounds__(256)
void softmax_packed(u16* __restrict__ sc)
{
  const int rowid = blockIdx.x;            // b*2048 + i
  const int b = rowid >> 11, i = rowid & 2047;
  const int mtt = i >> 7, rr = i & 127;
  u16* base = sc + (long)b * BATCH_SC + (long)(mtt * (mtt + 1) / 2) * 16384 + rr * 128;
  const int t = threadIdx.x;
  const int lane = t & 63, wv = t >> 6;
  const int L = i + 1, Lpad = (mtt + 1) << 7;
  float vals[8];
  float m = -1e30f;
#pragma unroll
  for (int u = 0; u < 8; ++u) {
    const int j = t + u * 256;
    if (j < L) { vals[u] = bf2f(base[(j >> 7) * 16384 + (j & 127)]); m = fmaxf(m, vals[u]); }
    else vals[u] = -1e30f;
  }
#pragma unroll
  for (int o = 1; o < 64; o <<= 1) m = fmaxf(m, __shfl_xor(m, o));
  __shared__ float rm[4], rsm[4];
  if (lane == 0) rm[wv] = m;
  __syncthreads();
  m = fmaxf(fmaxf(rm[0], rm[1]), fmaxf(rm[2], rm[3]));
  float pv[8];
  float ssum = 0.f;
#pragma unroll
  for (int u = 0; u < 8; ++u) { pv[u] = expf(vals[u] - m); ssum += pv[u]; }
#pragma unroll
  for (int o = 1; o < 64; o <<= 1) ssum += __shfl_xor(ssum, o);
  if (lane == 0) rsm[wv] = ssum;
  __syncthreads();   // all reads complete before writes
  ssum = rsm[0] + rsm[1] + rsm[2] + rsm[3];
  const float inv = 1.f / ssum;
#pragma unroll
  for (int u = 0; u < 8; ++u) {
    const int j = t + u * 256;
    if (j < Lpad) base[(j >> 7) * 16384 + (j & 127)] = f2bf(pv[u] * inv);
  }
}

// ---------- LayerNorm rows of 1024; OUTBF: 1 = bf16 out ----------
template<int OUTBF>
__global__ __launch_bounds__(256)
void layernorm_k(const float* __restrict__ in, const float* __restrict__ gam,
                 const float* __restrict__ bet, void* __restrict__ outv)
{
  const long row = blockIdx.x;
  const int t = threadIdx.x;
  const int lane = t & 63, wv = t >> 6;
  const float4 v = ((const float4*)(in + row * 1024))[t];
  float s = v.x + v.y + v.z + v.w;
  float q = v.x * v.x + v.y * v.y + v.z * v.z + v.w * v.w;
#pragma unroll
  for (int o = 1; o < 64; o <<= 1) { s += __shfl_xor(s, o); q += __shfl_xor(q, o); }
  __shared__ float rs[4], rq[4];
  if (lane == 0) { rs[wv] = s; rq[wv] = q; }
  __syncthreads();
  s = rs[0] + rs[1] + rs[2] + rs[3];
  q = rq[0] + rq[1] + rq[2] + rq[3];
  const float mean = s * (1.f / 1024.f);
  const float var  = q * (1.f / 1024.f) - mean * mean;
  const float rstd = rsqrtf(var + 1e-5f);
  const float4 g4 = ((const float4*)gam)[t];
  const float4 b4 = ((const float4*)bet)[t];
  const float o0 = (v.x - mean) * rstd * g4.x + b4.x;
  const float o1 = (v.y - mean) * rstd * g4.y + b4.y;
  const float o2 = (v.z - mean) * rstd * g4.z + b4.z;
  const float o3 = (v.w - mean) * rstd * g4.w + b4.w;
  if (OUTBF) {
    ushort4 o; o.x = f2bf(o0); o.y = f2bf(o1); o.z = f2bf(o2); o.w = f2bf(o3);
    ((ushort4*)outv)[row * 256 + t] = o;
  } else {
    ((float4*)outv)[row * 256 + t] = make_float4(o0, o1, o2, o3);
  }
}

// =====================================================================
extern "C" void kernel_launch(void* const* d_in, const int* in_sizes, int n_in,
                              void* d_out, int out_size, void* d_ws, size_t ws_size,
                              hipStream_t stream)
{
  const float* x   = (const float*)d_in[0];
  const float* Wq  = (const float*)d_in[1];
  const float* bq  = (const float*)d_in[2];
  const float* Wk  = (const float*)d_in[3];
  const float* bk  = (const float*)d_in[4];
  const float* Wv  = (const float*)d_in[5];
  const float* bv  = (const float*)d_in[6];
  const float* W1  = (const float*)d_in[7];
  const float* b1  = (const float*)d_in[8];
  const float* W2  = (const float*)d_in[9];
  const float* b2  = (const float*)d_in[10];
  const float* g1  = (const float*)d_in[11];
  const float* be1 = (const float*)d_in[12];
  const float* g2  = (const float*)d_in[13];
  const float* be2 = (const float*)d_in[14];

  // workspace (peak ~152 MiB), stream-ordered reuse:
  //  [0,32M)    xb (x bf16) -> vt (v^T) after QKV
  //  [32,64M)   q -> ln1 (after scores / after PV)
  //  [64,96M)   k -> h[0:32M) (FFN half-hidden, after scores)
  //  [96,128M)  v -> sc[0:32M) (after v-transpose) -> h[32:64M)
  //  [128,130M) sc tail (packed causal bf16 scores, 34 MiB total)
  //  [130..152M) bf16 [N][K] weights: Wqkv(6M) | W1T(8M) | W2T(8M)
  char* ws = (char*)d_ws;
  u16*   xb    = (u16*)(ws);
  u16*   vt    = xb;
  u16*   qkv   = (u16*)(ws + 33554432);          // q|k|v contiguous (16M elems each)
  u16*   qbuf  = qkv;
  u16*   kbuf  = qkv + 16777216;
  u16*   vbuf  = qkv + 33554432;
  u16*   ln1   = qbuf;                            // over q
  u16*   hbuf  = kbuf;                            // 64 MiB over k+v/sc
  u16*   sc    = (u16*)(ws + 100663296);          // packed scores over dead v
  u16*   wqkvT = (u16*)(ws + 136314880);
  u16*   w1T   = (u16*)(ws + 142606336);
  u16*   w2T   = (u16*)(ws + 150994944);
  float* attnf = (float*)d_out;                   // PV out f32 lives in d_out

  const dim3 B256(256);

  // 1. x -> bf16
  cvt_f32_to_bf16<<<dim3(16384), B256, 0, stream>>>(x, xb, 16777216L);

  // 2. weight transposes: f32 [K][N] -> bf16 [N][K]
  transpose_bf16<0><<<dim3(32, 32, 1),  B256, 0, stream>>>(Wq, wqkvT,           1024, 1024, 0, 0);
  transpose_bf16<0><<<dim3(32, 32, 1),  B256, 0, stream>>>(Wk, wqkvT + 1048576, 1024, 1024, 0, 0);
  transpose_bf16<0><<<dim3(32, 32, 1),  B256, 0, stream>>>(Wv, wqkvT + 2097152, 1024, 1024, 0, 0);
  transpose_bf16<0><<<dim3(128, 32, 1), B256, 0, stream>>>(W1, w1T, 1024, 4096, 0, 0);
  transpose_bf16<0><<<dim3(32, 128, 1), B256, 0, stream>>>(W2, w2T, 4096, 1024, 0, 0);

  // 3. fused QKV projection: M=16384, N=3072, K=1024 (64x12 tiles, M-major)
  gemm256_p8<0><<<dim3(768), dim3(512), 0, stream>>>(xb, 1024, wqkvT, 1024, qkv, 1024,
                                                     bq, bk, bv, nullptr, 1024, 12);

  // 4. v -> v^T per batch (2048x1024 -> 1024x2048), over dead xb
  transpose_bf16<1><<<dim3(32, 64, 8), B256, 0, stream>>>(vbuf, vt, 2048, 1024, 2097152, 2097152);

  // 5. scores = q@k^T/32 -> packed causal bf16 (all batches)
  gemm_bt<1><<<dim3(16, 16, 8), B256, 0, stream>>>(qbuf, 1024, 2097152, kbuf, 1024, 2097152,
                                                   sc, 0, 0, 1024, 0.03125f);

  // 6. row softmax in place on packed tiles
  softmax_packed<<<dim3(16384), B256, 0, stream>>>(sc);

  // 7. attn = probs @ v -> f32 directly into d_out (block-causal Keff)
  gemm_bt<2><<<dim3(8, 16, 8), B256, 0, stream>>>(sc, 0, 0, vt, 2048, 2097152,
                                                  attnf, 1024, 2097152, 0, 1.f);

  // 8. LN1: d_out f32 -> ln1 bf16
  layernorm_k<1><<<dim3(16384), B256, 0, stream>>>(attnf, g1, be1, ln1);

  // 9. FFN split along N_ff into 2 halves of 2048; f32 accumulation in d_out.
  //    A/B experiment: half 0 via p8, half 1 via p2 (same shape -> direct compare).
  gemm256_p8<3><<<dim3(512), dim3(512), 0, stream>>>(ln1, 1024, w1T, 1024,
                                                     hbuf, 2048, b1, nullptr, nullptr,
                                                     nullptr, 1024, 8);
  gemm256_p8<4><<<dim3(256), dim3(512), 0, stream>>>(hbuf, 2048, w2T, 4096, d_out, 1024,
                                                     nullptr, nullptr, nullptr, nullptr, 2048, 4);
  gemm256_p2<3><<<dim3(512), dim3(512), 0, stream>>>(ln1, 1024, w1T + 2048LL * 1024, 1024,
                                                     hbuf, 2048, b1 + 2048, nullptr, nullptr,
                                                     nullptr, 1024, 8);
  gemm256_p8<5><<<dim3(256), dim3(512), 0, stream>>>(hbuf, 2048, w2T + 2048, 4096, d_out, 1024,
                                                     b2, nullptr, nullptr, ln1, 2048, 4);

  // 10. LN2 in place on d_out (f32)
  layernorm_k<0><<<dim3(16384), B256, 0, stream>>>((float*)d_out, g2, be2, d_out);
}

// Round 5
// 788.787 us; speedup vs baseline: 1.1611x; 1.1611x over previous
//
#include <hip/hip_runtime.h>
#include <cstdint>

#define DEV __device__ __forceinline__

typedef __attribute__((ext_vector_type(8))) short bf16x8;
typedef __attribute__((ext_vector_type(4))) float f32x4;
typedef unsigned short u16;
typedef unsigned int   u32;

// ---------- bf16 helpers (manual RNE) ----------
DEV u16 f2bf(float f) {
  u32 u = __float_as_uint(f);
  u = (u + 0x7FFFu + ((u >> 16) & 1u)) >> 16;
  return (u16)u;
}
DEV float bf2f(u16 s) { return __uint_as_float(((u32)s) << 16); }

DEV float gelu_f(float x) { return 0.5f * x * (1.f + erff(x * 0.70710678118654752f)); }

// ---------- async global->LDS (16B per lane) ----------
DEV void gload_lds16(const void* g, void* l) {
  typedef __attribute__((address_space(1))) const unsigned int GU;
  typedef __attribute__((address_space(3))) unsigned int LU;
  __builtin_amdgcn_global_load_lds((GU*)(uintptr_t)g, (LU*)(u32)(uintptr_t)l, 16, 0, 0);
}

// LDS byte swizzle for 256-tile kernel (proven conflict-free in R4)
DEV int swz(int x) { return x ^ (((x >> 7) & 7) << 4); }

// packed causal score layout: per batch, 136 lower-triangle 128x128 tiles,
// tile (mt,nt) nt<=mt at (mt*(mt+1)/2 + nt)*16384, row-major inside.
#define BATCH_SC 2228224L   // u16 elements per batch (136*16384)

// =====================================================================
// gemm_bt 128x128 (proven m97 structure, R2-measured 460 TF @K=1024)
// C[M,N] = A[M,K] @ Bt[N,K]^T, bf16 in, f32 accum. grid.z = batch.
// MODE 0: fused QKV -> bf16 +bias (bq/bk/bv routed by gc>>10, split outputs)
// MODE 1: scores = q@k^T*scale -> packed causal bf16 tiles
// MODE 2: attn = probs(packed)@vt^T -> f32, Keff=(mt+1)*128
// MODE 3: FFN1 -> bf16, +bias, gelu
// MODE 4: FFN2 -> f32 = v + bias + resid(bf16)   (single full-K pass)
// =====================================================================
template<int MODE>
__global__ __launch_bounds__(256, 4)
void gemm_bt(const u16* __restrict__ A, int lda, long abst,
             const u16* __restrict__ Bt, int ldb, long bbst,
             void* __restrict__ Cv, int ldc, long cbst,
             const float* __restrict__ bias,
             const float* __restrict__ bias2,
             const float* __restrict__ bias3,
             const u16* __restrict__ resid,
             int K, float scale)
{
  const int nt = blockIdx.x, mt = blockIdx.y, bz = blockIdx.z;
  if (MODE == 1 && nt > mt) return;
  const int Keff = (MODE == 2) ? (mt + 1) * 128 : K;

  __shared__ u16 As[128 * 64];
  __shared__ u16 Bs[128 * 64];

  const int tid  = threadIdx.x;
  const int lane = tid & 63;
  const int wv   = tid >> 6;
  const int wr   = wv >> 1, wc = wv & 1;
  const int lrow = lane & 15;
  const int kgrp = lane >> 4;
  const int m0 = mt * 128, n0 = nt * 128;

  const int srow = tid >> 3;
  const int scol = (tid & 7) * 8;
  const u16* Ag;
  if (MODE == 2) {  // packed probs: chunk (k0>>7) at tri-offset, row stride 128
    Ag = A + bz * BATCH_SC + (long)(mt * (mt + 1) / 2) * 16384 + srow * 128 + scol;
  } else {
    Ag = A + (long)bz * abst + (long)(m0 + srow) * lda + scol;
  }
  const u16* Bg = Bt + (long)bz * bbst + (long)(n0 + srow) * ldb + scol;
  char* AsW = (char*)As + wv * 1024;           // wave-uniform LDS base
  char* BsW = (char*)Bs + wv * 1024;

  f32x4 acc[4][4];
#pragma unroll
  for (int mi = 0; mi < 4; ++mi)
#pragma unroll
    for (int ni = 0; ni < 4; ++ni)
#pragma unroll
      for (int e = 0; e < 4; ++e) acc[mi][ni][e] = 0.f;

  for (int k0 = 0; k0 < Keff; k0 += 64) {
#pragma unroll
    for (int i = 0; i < 4; ++i) {
      if (MODE == 2)
        gload_lds16(Ag + (long)(k0 >> 7) * 16384 + (k0 & 127) + i * 32 * 128, AsW + i * 4096);
      else
        gload_lds16(Ag + k0 + (long)i * 32 * lda, AsW + i * 4096);
      gload_lds16(Bg + k0 + (long)i * 32 * ldb, BsW + i * 4096);
    }
    __syncthreads();
#pragma unroll
    for (int kk = 0; kk < 2; ++kk) {
      const int kof = kk * 32 + kgrp * 8;
      bf16x8 af[4], bfr[4];
#pragma unroll
      for (int mi = 0; mi < 4; ++mi)
        af[mi] = *(const bf16x8*)&As[(wr * 64 + mi * 16 + lrow) * 64 + kof];
#pragma unroll
      for (int ni = 0; ni < 4; ++ni)
        bfr[ni] = *(const bf16x8*)&Bs[(wc * 64 + ni * 16 + lrow) * 64 + kof];
#pragma unroll
      for (int mi = 0; mi < 4; ++mi)
#pragma unroll
        for (int ni = 0; ni < 4; ++ni)
          acc[mi][ni] = __builtin_amdgcn_mfma_f32_16x16x32_bf16(af[mi], bfr[ni], acc[mi][ni], 0, 0, 0);
    }
    __syncthreads();
  }

  // epilogue: C/D layout col=lane&15, row=(lane>>4)*4+e [m89]
#pragma unroll
  for (int mi = 0; mi < 4; ++mi) {
#pragma unroll
    for (int ni = 0; ni < 4; ++ni) {
#pragma unroll
      for (int e = 0; e < 4; ++e) {
        const int rr = wr * 64 + mi * 16 + kgrp * 4 + e;   // row in tile
        const int cc = wc * 64 + ni * 16 + lrow;           // col in tile
        const int gr = m0 + rr, gc = n0 + cc;
        const float v = acc[mi][ni][e];
        if (MODE == 0) {
          const float bval = gc < 1024 ? bias[gc]
                              : (gc < 2048 ? bias2[gc & 1023] : bias3[gc & 1023]);
          ((u16*)Cv)[(long)(gc >> 10) * 16777216 + (long)gr * 1024 + (gc & 1023)]
              = f2bf(v + bval);
        } else if (MODE == 1) {
          ((u16*)Cv)[bz * BATCH_SC + (long)(mt * (mt + 1) / 2 + nt) * 16384 + rr * 128 + cc]
              = f2bf(v * scale);
        } else if (MODE == 2) {
          ((float*)Cv)[(long)bz * cbst + (long)gr * ldc + gc] = v;
        } else if (MODE == 3) {
          ((u16*)Cv)[(long)gr * ldc + gc] = f2bf(gelu_f(v + bias[gc]));
        } else {
          ((float*)Cv)[(long)gr * ldc + gc] = v + bias[gc] + bf2f(resid[(long)gr * 1024 + gc]);
        }
      }
    }
  }
}

// =====================================================================
// gemm256_p8: 8-phase counted-vmcnt 256x256 pipeline (R4 structure),
// single purpose: FFN2 chunk (f32 = v + bias + resid), K deep (4096).
// Deployed at half-fill as a deep-K probe (per-CU rate vs gemm_bt).
// =====================================================================
__global__ __launch_bounds__(512, 2)
void gemm256_p8_ffn2(const u16* __restrict__ A, int lda,
                     const u16* __restrict__ Bt, int ldb,
                     float* __restrict__ Cv, int ldc,
                     const float* __restrict__ bias,
                     const u16* __restrict__ resid,
                     int K, int NNT)
{
  __shared__ char smem[131072];
  const int tid  = threadIdx.x;
  const int lane = tid & 63;
  const int wv   = tid >> 6;
  const int wm   = wv >> 2, wn = wv & 3;
  const int lrow = lane & 15;
  const int kgrp = lane >> 4;

  const int nwg = gridDim.x;
  const int q0 = nwg >> 3, r = nwg & 7, xc = blockIdx.x & 7, pos = blockIdx.x >> 3;
  const int s = (xc < r ? xc * (q0 + 1) : r * (q0 + 1) + (xc - r) * q0) + pos;
  const int mt = s / NNT, nt = s % NNT;
  const int m0 = mt * 256, n0 = nt * 256;

  auto stageA = [&](int ktile, int dslot, int h) {
    int k0 = ktile << 6; const int kmax = K - 64; if (k0 > kmax) k0 = kmax;
#pragma unroll
    for (int j = 0; j < 2; ++j) {
      const int o = j * 8192 + tid * 16;
      const int l = swz(o);
      gload_lds16(A + (long)(m0 + h * 128 + (l >> 7)) * lda + k0 + ((l & 127) >> 1),
                  smem + dslot * 65536 + h * 16384 + o);
    }
  };
  auto stageB = [&](int ktile, int dslot, int h) {
    int k0 = ktile << 6; const int kmax = K - 64; if (k0 > kmax) k0 = kmax;
#pragma unroll
    for (int j = 0; j < 2; ++j) {
      const int o = j * 8192 + tid * 16;
      const int l = swz(o);
      gload_lds16(Bt + (long)(n0 + h * 128 + (l >> 7)) * ldb + k0 + ((l & 127) >> 1),
                  smem + dslot * 65536 + 32768 + h * 16384 + o);
    }
  };
  auto rdfrag = [&](int bofs, int row, int ks) -> bf16x8 {
    const int p = swz(row * 128 + ks * 64 + kgrp * 16);
    return *(const bf16x8*)(smem + bofs + p);
  };

  f32x4 acc[8][4];
#pragma unroll
  for (int mi = 0; mi < 8; ++mi)
#pragma unroll
    for (int ni = 0; ni < 4; ++ni)
#pragma unroll
      for (int e = 0; e < 4; ++e) acc[mi][ni][e] = 0.f;

  stageA(0, 0, 0); stageA(0, 0, 1); stageB(0, 0, 0); stageB(0, 0, 1);
  stageB(1, 1, 0); stageB(1, 1, 1);
  asm volatile("s_waitcnt vmcnt(4)" ::: "memory");
  __builtin_amdgcn_s_barrier();

  const int NI = K >> 7;
  bf16x8 bfrag[4][2], afrag[2][2];
  for (int i = 0; i < NI; ++i) {
    const int kp = 2 * i;
#pragma unroll
    for (int d = 0; d < 2; ++d) {
#pragma unroll
      for (int mq = 0; mq < 4; ++mq) {
        const int ph = d * 4 + mq;
        if (mq == 0) {
#pragma unroll
          for (int ni = 0; ni < 4; ++ni)
#pragma unroll
            for (int ks = 0; ks < 2; ++ks)
              bfrag[ni][ks] = rdfrag(d * 65536 + 32768, wn * 64 + ni * 16 + lrow, ks);
        }
#pragma unroll
        for (int mi2 = 0; mi2 < 2; ++mi2)
#pragma unroll
          for (int ks = 0; ks < 2; ++ks)
            afrag[mi2][ks] = rdfrag(d * 65536, wm * 128 + (2 * mq + mi2) * 16 + lrow, ks);
        switch (ph) {
          case 0: stageA(kp + 1, 1, 0); break;
          case 1: stageA(kp + 1, 1, 1); break;
          case 2: stageB(kp + 2, 0, 0); break;
          case 3: stageB(kp + 2, 0, 1); break;
          case 4: stageA(kp + 2, 0, 0); break;
          case 5: stageA(kp + 2, 0, 1); break;
          case 6: stageB(kp + 3, 1, 0); break;
          case 7: stageB(kp + 3, 1, 1); break;
        }
        __builtin_amdgcn_s_barrier();
        asm volatile("s_waitcnt lgkmcnt(0)" ::: "memory");
        __builtin_amdgcn_s_setprio(1);
#pragma unroll
        for (int mi2 = 0; mi2 < 2; ++mi2)
#pragma unroll
          for (int ni = 0; ni < 4; ++ni)
#pragma unroll
            for (int ks = 0; ks < 2; ++ks)
              acc[2 * mq + mi2][ni] = __builtin_amdgcn_mfma_f32_16x16x32_bf16(
                  afrag[mi2][ks], bfrag[ni][ks], acc[2 * mq + mi2][ni], 0, 0, 0);
        __builtin_amdgcn_s_setprio(0);
        if (mq == 3) asm volatile("s_waitcnt vmcnt(4)" ::: "memory");
        __builtin_amdgcn_s_barrier();
      }
    }
  }

#pragma unroll
  for (int mi = 0; mi < 8; ++mi) {
#pragma unroll
    for (int ni = 0; ni < 4; ++ni) {
      const int gc = n0 + wn * 64 + ni * 16 + lrow;
#pragma unroll
      for (int e = 0; e < 4; ++e) {
        const int gr = m0 + wm * 128 + mi * 16 + kgrp * 4 + e;
        Cv[(long)gr * ldc + gc] = acc[mi][ni][e] + bias[gc]
                                  + bf2f(resid[(long)gr * 1024 + gc]);
      }
    }
  }
}

// ---------- transpose (+convert) to bf16 [C][R]; INBF: 0=f32, 1=bf16 ----------
template<int INBF>
__global__ __launch_bounds__(256)
void transpose_bf16(const void* __restrict__ inv, u16* __restrict__ out,
                    int R, int C, long ibst, long obst)
{
  __shared__ float t[32][33];
  const int bz = blockIdx.z;
  const int c0 = blockIdx.x * 32, r0 = blockIdx.y * 32;
  const int tx = threadIdx.x & 31, ty = threadIdx.x >> 5;
#pragma unroll
  for (int i = 0; i < 32; i += 8) {
    const long idx = (long)bz * ibst + (long)(r0 + ty + i) * C + (c0 + tx);
    t[ty + i][tx] = INBF ? bf2f(((const u16*)inv)[idx]) : ((const float*)inv)[idx];
  }
  __syncthreads();
#pragma unroll
  for (int i = 0; i < 32; i += 8)
    out[(long)bz * obst + (long)(c0 + ty + i) * R + (r0 + tx)] = f2bf(t[tx][ty + i]);
}

// ---------- f32 -> bf16 convert ----------
__global__ __launch_bounds__(256)
void cvt_f32_to_bf16(const float* __restrict__ in, u16* __restrict__ out, long n)
{
  const long idx = ((long)blockIdx.x * 256 + threadIdx.x) * 4;
  if (idx >= n) return;
  const float4 v = *(const float4*)(in + idx);
  ushort4 o;
  o.x = f2bf(v.x); o.y = f2bf(v.y); o.z = f2bf(v.z); o.w = f2bf(v.w);
  *(ushort4*)(out + idx) = o;
}

// ---------- causal row softmax on packed bf16 tiles, in place ----------
__global__ __launch_bounds__(256)
void softmax_packed(u16* __restrict__ sc)
{
  const int rowid = blockIdx.x;            // b*2048 + i
  const int b = rowid >> 11, i = rowid & 2047;
  const int mtt = i >> 7, rr = i & 127;
  u16* base = sc + (long)b * BATCH_SC + (long)(mtt * (mtt + 1) / 2) * 16384 + rr * 128;
  const int t = threadIdx.x;
  const int lane = t & 63, wv = t >> 6;
  const int L = i + 1, Lpad = (mtt + 1) << 7;
  float vals[8];
  float m = -1e30f;
#pragma unroll
  for (int u = 0; u < 8; ++u) {
    const int j = t + u * 256;
    if (j < L) { vals[u] = bf2f(base[(j >> 7) * 16384 + (j & 127)]); m = fmaxf(m, vals[u]); }
    else vals[u] = -1e30f;
  }
#pragma unroll
  for (int o = 1; o < 64; o <<= 1) m = fmaxf(m, __shfl_xor(m, o));
  __shared__ float rm[4], rsm[4];
  if (lane == 0) rm[wv] = m;
  __syncthreads();
  m = fmaxf(fmaxf(rm[0], rm[1]), fmaxf(rm[2], rm[3]));
  float pv[8];
  float ssum = 0.f;
#pragma unroll
  for (int u = 0; u < 8; ++u) { pv[u] = expf(vals[u] - m); ssum += pv[u]; }
#pragma unroll
  for (int o = 1; o < 64; o <<= 1) ssum += __shfl_xor(ssum, o);
  if (lane == 0) rsm[wv] = ssum;
  __syncthreads();   // all reads complete before writes
  ssum = rsm[0] + rsm[1] + rsm[2] + rsm[3];
  const float inv = 1.f / ssum;
#pragma unroll
  for (int u = 0; u < 8; ++u) {
    const int j = t + u * 256;
    if (j < Lpad) base[(j >> 7) * 16384 + (j & 127)] = f2bf(pv[u] * inv);
  }
}

// ---------- LayerNorm rows of 1024; OUTBF: 1 = bf16 out ----------
template<int OUTBF>
__global__ __launch_bounds__(256)
void layernorm_k(const float* __restrict__ in, const float* __restrict__ gam,
                 const float* __restrict__ bet, void* __restrict__ outv)
{
  const long row = blockIdx.x;
  const int t = threadIdx.x;
  const int lane = t & 63, wv = t >> 6;
  const float4 v = ((const float4*)(in + row * 1024))[t];
  float s = v.x + v.y + v.z + v.w;
  float q = v.x * v.x + v.y * v.y + v.z * v.z + v.w * v.w;
#pragma unroll
  for (int o = 1; o < 64; o <<= 1) { s += __shfl_xor(s, o); q += __shfl_xor(q, o); }
  __shared__ float rs[4], rq[4];
  if (lane == 0) { rs[wv] = s; rq[wv] = q; }
  __syncthreads();
  s = rs[0] + rs[1] + rs[2] + rs[3];
  q = rq[0] + rq[1] + rq[2] + rq[3];
  const float mean = s * (1.f / 1024.f);
  const float var  = q * (1.f / 1024.f) - mean * mean;
  const float rstd = rsqrtf(var + 1e-5f);
  const float4 g4 = ((const float4*)gam)[t];
  const float4 b4 = ((const float4*)bet)[t];
  const float o0 = (v.x - mean) * rstd * g4.x + b4.x;
  const float o1 = (v.y - mean) * rstd * g4.y + b4.y;
  const float o2 = (v.z - mean) * rstd * g4.z + b4.z;
  const float o3 = (v.w - mean) * rstd * g4.w + b4.w;
  if (OUTBF) {
    ushort4 o; o.x = f2bf(o0); o.y = f2bf(o1); o.z = f2bf(o2); o.w = f2bf(o3);
    ((ushort4*)outv)[row * 256 + t] = o;
  } else {
    ((float4*)outv)[row * 256 + t] = make_float4(o0, o1, o2, o3);
  }
}

// =====================================================================
extern "C" void kernel_launch(void* const* d_in, const int* in_sizes, int n_in,
                              void* d_out, int out_size, void* d_ws, size_t ws_size,
                              hipStream_t stream)
{
  const float* x   = (const float*)d_in[0];
  const float* Wq  = (const float*)d_in[1];
  const float* bq  = (const float*)d_in[2];
  const float* Wk  = (const float*)d_in[3];
  const float* bk  = (const float*)d_in[4];
  const float* Wv  = (const float*)d_in[5];
  const float* bv  = (const float*)d_in[6];
  const float* W1  = (const float*)d_in[7];
  const float* b1  = (const float*)d_in[8];
  const float* W2  = (const float*)d_in[9];
  const float* b2  = (const float*)d_in[10];
  const float* g1  = (const float*)d_in[11];
  const float* be1 = (const float*)d_in[12];
  const float* g2  = (const float*)d_in[13];
  const float* be2 = (const float*)d_in[14];

  // workspace (peak ~152 MiB), stream-ordered reuse (R3/R4-proven):
  //  [0,32M)    xb (x bf16) -> vt (v^T bf16) after QKV
  //  [32,64M)   q -> ln1
  //  [64,96M)   k -> h[0:32M)
  //  [96,128M)  v -> sc[0:32M) -> h[32:64M)
  //  [128,130M) sc tail (packed causal bf16, 34 MiB total from 96M)
  //  [130..152M) bf16 [N][K] weights: Wqkv(6M) | W1T(8M) | W2T(8M)
  char* ws = (char*)d_ws;
  u16*   xb    = (u16*)(ws);
  u16*   vt    = xb;
  u16*   qkv   = (u16*)(ws + 33554432);
  u16*   qbuf  = qkv;
  u16*   kbuf  = qkv + 16777216;
  u16*   vbuf  = qkv + 33554432;
  u16*   ln1   = qbuf;
  u16*   hbuf  = kbuf;                            // 64 MiB over k + v/sc
  u16*   sc    = (u16*)(ws + 100663296);
  u16*   wqkvT = (u16*)(ws + 136314880);
  u16*   w1T   = (u16*)(ws + 142606336);
  u16*   w2T   = (u16*)(ws + 150994944);
  float* attnf = (float*)d_out;

  const dim3 B256(256);

  // 1. x -> bf16
  cvt_f32_to_bf16<<<dim3(16384), B256, 0, stream>>>(x, xb, 16777216L);

  // 2. weight transposes: f32 [K][N] -> bf16 [N][K]
  transpose_bf16<0><<<dim3(32, 32, 1),  B256, 0, stream>>>(Wq, wqkvT,           1024, 1024, 0, 0);
  transpose_bf16<0><<<dim3(32, 32, 1),  B256, 0, stream>>>(Wk, wqkvT + 1048576, 1024, 1024, 0, 0);
  transpose_bf16<0><<<dim3(32, 32, 1),  B256, 0, stream>>>(Wv, wqkvT + 2097152, 1024, 1024, 0, 0);
  transpose_bf16<0><<<dim3(128, 32, 1), B256, 0, stream>>>(W1, w1T, 1024, 4096, 0, 0);
  transpose_bf16<0><<<dim3(32, 128, 1), B256, 0, stream>>>(W2, w2T, 4096, 1024, 0, 0);

  // 3. fused QKV: M=16384, N=3072, K=1024 (grid 24x128 = 3072 blocks)
  gemm_bt<0><<<dim3(24, 128), B256, 0, stream>>>(xb, 1024, 0, wqkvT, 1024, 0, qkv, 1024, 0,
                                                 bq, bk, bv, nullptr, 1024, 1.f);

  // 4. v -> v^T per batch, over dead xb
  transpose_bf16<1><<<dim3(32, 64, 8), B256, 0, stream>>>(vbuf, vt, 2048, 1024, 2097152, 2097152);

  // 5. scores = q@k^T/32 -> packed causal bf16 (all batches)
  gemm_bt<1><<<dim3(16, 16, 8), B256, 0, stream>>>(qbuf, 1024, 2097152, kbuf, 1024, 2097152,
                                                   sc, 0, 0, nullptr, nullptr, nullptr, nullptr,
                                                   1024, 0.03125f);

  // 6. row softmax in place on packed tiles
  softmax_packed<<<dim3(16384), B256, 0, stream>>>(sc);

  // 7. attn = probs @ v -> f32 into d_out (block-causal Keff)
  gemm_bt<2><<<dim3(8, 16, 8), B256, 0, stream>>>(sc, 0, 0, vt, 2048, 2097152,
                                                  attnf, 1024, 2097152, nullptr, nullptr, nullptr,
                                                  nullptr, 0, 1.f);

  // 8. LN1: d_out f32 -> ln1 bf16
  layernorm_k<1><<<dim3(16384), B256, 0, stream>>>(attnf, g1, be1, ln1);

  // 9. FFN in 2 M-chunks of 8192 (h reuses 64 MiB). FFN2 A/B experiment:
  //    chunk 0 via 128x128 gemm_bt (512 blocks, 2/CU), chunk 1 via 256x256
  //    p8 (128 blocks, 0.5/CU) -> compare per-CU rates at K=4096.
  for (int c = 0; c < 2; ++c) {
    const u16* lc = ln1 + (long)c * 8192 * 1024;
    float* oc = (float*)d_out + (long)c * 8192 * 1024;
    // h = gelu(ln1 @ W1 + b1): M=8192, N=4096, K=1024 (grid 32x64 = 2048 blocks)
    gemm_bt<3><<<dim3(32, 64), B256, 0, stream>>>(lc, 1024, 0, w1T, 1024, 0, hbuf, 4096, 0,
                                                  b1, nullptr, nullptr, nullptr, 1024, 1.f);
    // out = h @ W2 + b2 + ln1: M=8192, N=1024, K=4096
    if (c == 0)
      gemm_bt<4><<<dim3(8, 64), B256, 0, stream>>>(hbuf, 4096, 0, w2T, 4096, 0, oc, 1024, 0,
                                                   b2, nullptr, nullptr, lc, 4096, 1.f);
    else
      gemm256_p8_ffn2<<<dim3(128), dim3(512), 0, stream>>>(hbuf, 4096, w2T, 4096, oc, 1024,
                                                           b2, lc, 4096, 4);
  }

  // 10. LN2 in place on d_out (f32)
  layernorm_k<0><<<dim3(16384), B256, 0, stream>>>((float*)d_out, g2, be2, d_out);
}

// Round 6
// 745.282 us; speedup vs baseline: 1.2289x; 1.0584x over previous
//
#include <hip/hip_runtime.h>
#include <cstdint>

#define DEV __device__ __forceinline__

typedef __attribute__((ext_vector_type(8))) short bf16x8;
typedef __attribute__((ext_vector_type(4))) float f32x4;
typedef unsigned short u16;
typedef unsigned int   u32;

// ---------- bf16 helpers (manual RNE) ----------
DEV u16 f2bf(float f) {
  u32 u = __float_as_uint(f);
  u = (u + 0x7FFFu + ((u >> 16) & 1u)) >> 16;
  return (u16)u;
}
DEV float bf2f(u16 s) { return __uint_as_float(((u32)s) << 16); }

// branch-free gelu via Abramowitz-Stegun 7.1.26 erf (|eps| <= 1.5e-7)
DEV float gelu_f(float x) {
  const float ax = fabsf(x) * 0.70710678118654752f;
  const float t = 1.f / fmaf(0.3275911f, ax, 1.f);
  float p = fmaf(1.061405429f, t, -1.453152027f);
  p = fmaf(p, t, 1.421413741f);
  p = fmaf(p, t, -0.284496736f);
  p = fmaf(p, t, 0.254829592f);
  p *= t;
  const float er = 1.f - p * __expf(-ax * ax);   // erf(|x|/sqrt2)
  const float erfx = copysignf(er, x);
  return 0.5f * x * (1.f + erfx);
}

// ---------- async global->LDS (16B per lane) ----------
DEV void gload_lds16(const void* g, void* l) {
  typedef __attribute__((address_space(1))) const unsigned int GU;
  typedef __attribute__((address_space(3))) unsigned int LU;
  __builtin_amdgcn_global_load_lds((GU*)(uintptr_t)g, (LU*)(u32)(uintptr_t)l, 16, 0, 0);
}

// LDS byte swizzle for 256-tile kernel (proven conflict-free in R4)
DEV int swz(int x) { return x ^ (((x >> 7) & 7) << 4); }

// packed causal score layout: per batch, 136 lower-triangle 128x128 tiles,
// tile (mt,nt) nt<=mt at (mt*(mt+1)/2 + nt)*16384, row-major inside.
#define BATCH_SC 2228224L   // u16 elements per batch (136*16384)

// =====================================================================
// gemm_bt 128x128 (m97 structure; measured 767 TF @K=1024 full-grid)
// C[M,N] = A[M,K] @ Bt[N,K]^T, bf16 in, f32 accum. grid.z = batch.
// MODE 0: fused QKV -> bf16 +bias (bq/bk/bv routed by gc>>10, split outputs)
// MODE 1: scores = q@k^T*scale -> packed causal bf16 tiles
// MODE 2: attn = probs(packed)@vt^T -> f32, Keff=(mt+1)*128
// MODE 3: FFN1 -> bf16, +bias, gelu
// =====================================================================
template<int MODE>
__global__ __launch_bounds__(256, 4)
void gemm_bt(const u16* __restrict__ A, int lda, long abst,
             const u16* __restrict__ Bt, int ldb, long bbst,
             void* __restrict__ Cv, int ldc, long cbst,
             const float* __restrict__ bias,
             const float* __restrict__ bias2,
             const float* __restrict__ bias3,
             const u16* __restrict__ resid,
             int K, float scale)
{
  const int nt = blockIdx.x, mt = blockIdx.y, bz = blockIdx.z;
  if (MODE == 1 && nt > mt) return;
  const int Keff = (MODE == 2) ? (mt + 1) * 128 : K;

  __shared__ u16 As[128 * 64];
  __shared__ u16 Bs[128 * 64];

  const int tid  = threadIdx.x;
  const int lane = tid & 63;
  const int wv   = tid >> 6;
  const int wr   = wv >> 1, wc = wv & 1;
  const int lrow = lane & 15;
  const int kgrp = lane >> 4;
  const int m0 = mt * 128, n0 = nt * 128;

  const int srow = tid >> 3;
  const int scol = (tid & 7) * 8;
  const u16* Ag;
  if (MODE == 2) {  // packed probs: chunk (k0>>7) at tri-offset, row stride 128
    Ag = A + bz * BATCH_SC + (long)(mt * (mt + 1) / 2) * 16384 + srow * 128 + scol;
  } else {
    Ag = A + (long)bz * abst + (long)(m0 + srow) * lda + scol;
  }
  const u16* Bg = Bt + (long)bz * bbst + (long)(n0 + srow) * ldb + scol;
  char* AsW = (char*)As + wv * 1024;           // wave-uniform LDS base
  char* BsW = (char*)Bs + wv * 1024;

  f32x4 acc[4][4];
#pragma unroll
  for (int mi = 0; mi < 4; ++mi)
#pragma unroll
    for (int ni = 0; ni < 4; ++ni)
#pragma unroll
      for (int e = 0; e < 4; ++e) acc[mi][ni][e] = 0.f;

  for (int k0 = 0; k0 < Keff; k0 += 64) {
#pragma unroll
    for (int i = 0; i < 4; ++i) {
      if (MODE == 2)
        gload_lds16(Ag + (long)(k0 >> 7) * 16384 + (k0 & 127) + i * 32 * 128, AsW + i * 4096);
      else
        gload_lds16(Ag + k0 + (long)i * 32 * lda, AsW + i * 4096);
      gload_lds16(Bg + k0 + (long)i * 32 * ldb, BsW + i * 4096);
    }
    __syncthreads();
#pragma unroll
    for (int kk = 0; kk < 2; ++kk) {
      const int kof = kk * 32 + kgrp * 8;
      bf16x8 af[4], bfr[4];
#pragma unroll
      for (int mi = 0; mi < 4; ++mi)
        af[mi] = *(const bf16x8*)&As[(wr * 64 + mi * 16 + lrow) * 64 + kof];
#pragma unroll
      for (int ni = 0; ni < 4; ++ni)
        bfr[ni] = *(const bf16x8*)&Bs[(wc * 64 + ni * 16 + lrow) * 64 + kof];
#pragma unroll
      for (int mi = 0; mi < 4; ++mi)
#pragma unroll
        for (int ni = 0; ni < 4; ++ni)
          acc[mi][ni] = __builtin_amdgcn_mfma_f32_16x16x32_bf16(af[mi], bfr[ni], acc[mi][ni], 0, 0, 0);
    }
    __syncthreads();
  }

  // epilogue: C/D layout col=lane&15, row=(lane>>4)*4+e [m89]
#pragma unroll
  for (int mi = 0; mi < 4; ++mi) {
#pragma unroll
    for (int ni = 0; ni < 4; ++ni) {
#pragma unroll
      for (int e = 0; e < 4; ++e) {
        const int rr = wr * 64 + mi * 16 + kgrp * 4 + e;   // row in tile
        const int cc = wc * 64 + ni * 16 + lrow;           // col in tile
        const int gr = m0 + rr, gc = n0 + cc;
        const float v = acc[mi][ni][e];
        if (MODE == 0) {
          const float bval = gc < 1024 ? bias[gc]
                              : (gc < 2048 ? bias2[gc & 1023] : bias3[gc & 1023]);
          ((u16*)Cv)[(long)(gc >> 10) * 16777216 + (long)gr * 1024 + (gc & 1023)]
              = f2bf(v + bval);
        } else if (MODE == 1) {
          ((u16*)Cv)[bz * BATCH_SC + (long)(mt * (mt + 1) / 2 + nt) * 16384 + rr * 128 + cc]
              = f2bf(v * scale);
        } else if (MODE == 2) {
          ((float*)Cv)[(long)bz * cbst + (long)gr * ldc + gc] = v;
        } else if (MODE == 3) {
          ((u16*)Cv)[(long)gr * ldc + gc] = f2bf(gelu_f(v + bias[gc]));
        }
      }
    }
  }
}

// =====================================================================
// gemm256_p8_ffn2: 8-phase counted-vmcnt 256x256 pipeline, FFN2 halves.
// Full-fill grid 256 (1 block/CU), K=2048 (NI=16).
// PASS 0: Cv = acc (raw partial)
// PASS 1: Cv += acc + bias + resid(bf16)
// =====================================================================
template<int PASS>
__global__ __launch_bounds__(512, 2)
void gemm256_p8_ffn2(const u16* __restrict__ A, int lda,
                     const u16* __restrict__ Bt, int ldb,
                     float* __restrict__ Cv, int ldc,
                     const float* __restrict__ bias,
                     const u16* __restrict__ resid,
                     int K, int NNT)
{
  __shared__ char smem[131072];
  const int tid  = threadIdx.x;
  const int lane = tid & 63;
  const int wv   = tid >> 6;
  const int wm   = wv >> 2, wn = wv & 3;
  const int lrow = lane & 15;
  const int kgrp = lane >> 4;

  const int nwg = gridDim.x;
  const int q0 = nwg >> 3, r = nwg & 7, xc = blockIdx.x & 7, pos = blockIdx.x >> 3;
  const int s = (xc < r ? xc * (q0 + 1) : r * (q0 + 1) + (xc - r) * q0) + pos;
  const int mt = s / NNT, nt = s % NNT;   // M-major: neighbors share A panel
  const int m0 = mt * 256, n0 = nt * 256;

  auto stageA = [&](int ktile, int dslot, int h) {
    int k0 = ktile << 6; const int kmax = K - 64; if (k0 > kmax) k0 = kmax;
#pragma unroll
    for (int j = 0; j < 2; ++j) {
      const int o = j * 8192 + tid * 16;
      const int l = swz(o);
      gload_lds16(A + (long)(m0 + h * 128 + (l >> 7)) * lda + k0 + ((l & 127) >> 1),
                  smem + dslot * 65536 + h * 16384 + o);
    }
  };
  auto stageB = [&](int ktile, int dslot, int h) {
    int k0 = ktile << 6; const int kmax = K - 64; if (k0 > kmax) k0 = kmax;
#pragma unroll
    for (int j = 0; j < 2; ++j) {
      const int o = j * 8192 + tid * 16;
      const int l = swz(o);
      gload_lds16(Bt + (long)(n0 + h * 128 + (l >> 7)) * ldb + k0 + ((l & 127) >> 1),
                  smem + dslot * 65536 + 32768 + h * 16384 + o);
    }
  };
  auto rdfrag = [&](int bofs, int row, int ks) -> bf16x8 {
    const int p = swz(row * 128 + ks * 64 + kgrp * 16);
    return *(const bf16x8*)(smem + bofs + p);
  };

  f32x4 acc[8][4];
#pragma unroll
  for (int mi = 0; mi < 8; ++mi)
#pragma unroll
    for (int ni = 0; ni < 4; ++ni)
#pragma unroll
      for (int e = 0; e < 4; ++e) acc[mi][ni][e] = 0.f;

  stageA(0, 0, 0); stageA(0, 0, 1); stageB(0, 0, 0); stageB(0, 0, 1);
  stageB(1, 1, 0); stageB(1, 1, 1);
  asm volatile("s_waitcnt vmcnt(4)" ::: "memory");
  __builtin_amdgcn_s_barrier();

  const int NI = K >> 7;
  bf16x8 bfrag[4][2], afrag[2][2];
  for (int i = 0; i < NI; ++i) {
    const int kp = 2 * i;
#pragma unroll
    for (int d = 0; d < 2; ++d) {
#pragma unroll
      for (int mq = 0; mq < 4; ++mq) {
        const int ph = d * 4 + mq;
        if (mq == 0) {
#pragma unroll
          for (int ni = 0; ni < 4; ++ni)
#pragma unroll
            for (int ks = 0; ks < 2; ++ks)
              bfrag[ni][ks] = rdfrag(d * 65536 + 32768, wn * 64 + ni * 16 + lrow, ks);
        }
#pragma unroll
        for (int mi2 = 0; mi2 < 2; ++mi2)
#pragma unroll
          for (int ks = 0; ks < 2; ++ks)
            afrag[mi2][ks] = rdfrag(d * 65536, wm * 128 + (2 * mq + mi2) * 16 + lrow, ks);
        switch (ph) {
          case 0: stageA(kp + 1, 1, 0); break;
          case 1: stageA(kp + 1, 1, 1); break;
          case 2: stageB(kp + 2, 0, 0); break;
          case 3: stageB(kp + 2, 0, 1); break;
          case 4: stageA(kp + 2, 0, 0); break;
          case 5: stageA(kp + 2, 0, 1); break;
          case 6: stageB(kp + 3, 1, 0); break;
          case 7: stageB(kp + 3, 1, 1); break;
        }
        __builtin_amdgcn_s_barrier();
        asm volatile("s_waitcnt lgkmcnt(0)" ::: "memory");
        __builtin_amdgcn_s_setprio(1);
#pragma unroll
        for (int mi2 = 0; mi2 < 2; ++mi2)
#pragma unroll
          for (int ni = 0; ni < 4; ++ni)
#pragma unroll
            for (int ks = 0; ks < 2; ++ks)
              acc[2 * mq + mi2][ni] = __builtin_amdgcn_mfma_f32_16x16x32_bf16(
                  afrag[mi2][ks], bfrag[ni][ks], acc[2 * mq + mi2][ni], 0, 0, 0);
        __builtin_amdgcn_s_setprio(0);
        if (mq == 3) asm volatile("s_waitcnt vmcnt(4)" ::: "memory");
        __builtin_amdgcn_s_barrier();
      }
    }
  }

#pragma unroll
  for (int mi = 0; mi < 8; ++mi) {
#pragma unroll
    for (int ni = 0; ni < 4; ++ni) {
      const int gc = n0 + wn * 64 + ni * 16 + lrow;
#pragma unroll
      for (int e = 0; e < 4; ++e) {
        const int gr = m0 + wm * 128 + mi * 16 + kgrp * 4 + e;
        if (PASS == 0) {
          Cv[(long)gr * ldc + gc] = acc[mi][ni][e];
        } else {
          float* o = &Cv[(long)gr * ldc + gc];
          *o = *o + acc[mi][ni][e] + bias[gc] + bf2f(resid[(long)gr * 1024 + gc]);
        }
      }
    }
  }
}

// ---------- transpose (+convert) to bf16 [C][R]; INBF: 0=f32, 1=bf16 ----------
template<int INBF>
__global__ __launch_bounds__(256)
void transpose_bf16(const void* __restrict__ inv, u16* __restrict__ out,
                    int R, int C, long ibst, long obst)
{
  __shared__ float t[32][33];
  const int bz = blockIdx.z;
  const int c0 = blockIdx.x * 32, r0 = blockIdx.y * 32;
  const int tx = threadIdx.x & 31, ty = threadIdx.x >> 5;
#pragma unroll
  for (int i = 0; i < 32; i += 8) {
    const long idx = (long)bz * ibst + (long)(r0 + ty + i) * C + (c0 + tx);
    t[ty + i][tx] = INBF ? bf2f(((const u16*)inv)[idx]) : ((const float*)inv)[idx];
  }
  __syncthreads();
#pragma unroll
  for (int i = 0; i < 32; i += 8)
    out[(long)bz * obst + (long)(c0 + ty + i) * R + (r0 + tx)] = f2bf(t[tx][ty + i]);
}

// ---------- f32 -> bf16 convert ----------
__global__ __launch_bounds__(256)
void cvt_f32_to_bf16(const float* __restrict__ in, u16* __restrict__ out, long n)
{
  const long idx = ((long)blockIdx.x * 256 + threadIdx.x) * 4;
  if (idx >= n) return;
  const float4 v = *(const float4*)(in + idx);
  ushort4 o;
  o.x = f2bf(v.x); o.y = f2bf(v.y); o.z = f2bf(v.z); o.w = f2bf(v.w);
  *(ushort4*)(out + idx) = o;
}

// ---------- causal row softmax on packed bf16 tiles, in place (vectorized) ----------
__global__ __launch_bounds__(256)
void softmax_packed(u16* __restrict__ sc)
{
  const int rowid = blockIdx.x;            // b*2048 + i
  const int b = rowid >> 11, i = rowid & 2047;
  const int mtt = i >> 7, rr = i & 127;
  u16* base = sc + (long)b * BATCH_SC + (long)(mtt * (mtt + 1) / 2) * 16384 + (long)rr * 128;
  const int t = threadIdx.x;
  const int lane = t & 63, wv = t >> 6;
  const int c   = t >> 4;                  // tile-chunk 0..15 (16 threads each)
  const int off = (t & 15) * 8;            // 8 contiguous elems per thread
  const bool act = (c <= mtt);
  // #valid elems in this thread's 8: full chunks -> 8; boundary chunk -> rr-off+1
  const int lim = (c < mtt) ? 8 : (c == mtt ? (rr - off + 1) : 0);
  u16* p = base + (long)c * 16384 + off;

  bf16x8 vv = {};
  if (act) vv = *(const bf16x8*)p;         // one 16B load
  float vals[8];
  float m = -1e30f;
#pragma unroll
  for (int e = 0; e < 8; ++e) {
    vals[e] = (e < lim) ? bf2f((u16)vv[e]) : -1e30f;
    m = fmaxf(m, vals[e]);
  }
#pragma unroll
  for (int o = 1; o < 64; o <<= 1) m = fmaxf(m, __shfl_xor(m, o));
  __shared__ float rm[4], rsm[4];
  if (lane == 0) rm[wv] = m;
  __syncthreads();
  m = fmaxf(fmaxf(rm[0], rm[1]), fmaxf(rm[2], rm[3]));
  float pv[8];
  float ssum = 0.f;
#pragma unroll
  for (int e = 0; e < 8; ++e) { pv[e] = __expf(vals[e] - m); ssum += pv[e]; }
#pragma unroll
  for (int o = 1; o < 64; o <<= 1) ssum += __shfl_xor(ssum, o);
  if (lane == 0) rsm[wv] = ssum;
  __syncthreads();   // all reads complete before writes
  ssum = rsm[0] + rsm[1] + rsm[2] + rsm[3];
  const float inv = 1.f / ssum;
  if (act) {
    bf16x8 o;
#pragma unroll
    for (int e = 0; e < 8; ++e) o[e] = (short)f2bf(pv[e] * inv);  // invalid -> exp(-huge)=0
    *(bf16x8*)p = o;                        // one 16B store
  }
}

// ---------- LayerNorm rows of 1024; OUTBF: 1 = bf16 out ----------
template<int OUTBF>
__global__ __launch_bounds__(256)
void layernorm_k(const float* __restrict__ in, const float* __restrict__ gam,
                 const float* __restrict__ bet, void* __restrict__ outv)
{
  const long row = blockIdx.x;
  const int t = threadIdx.x;
  const int lane = t & 63, wv = t >> 6;
  const float4 v = ((const float4*)(in + row * 1024))[t];
  float s = v.x + v.y + v.z + v.w;
  float q = v.x * v.x + v.y * v.y + v.z * v.z + v.w * v.w;
#pragma unroll
  for (int o = 1; o < 64; o <<= 1) { s += __shfl_xor(s, o); q += __shfl_xor(q, o); }
  __shared__ float rs[4], rq[4];
  if (lane == 0) { rs[wv] = s; rq[wv] = q; }
  __syncthreads();
  s = rs[0] + rs[1] + rs[2] + rs[3];
  q = rq[0] + rq[1] + rq[2] + rq[3];
  const float mean = s * (1.f / 1024.f);
  const float var  = q * (1.f / 1024.f) - mean * mean;
  const float rstd = rsqrtf(var + 1e-5f);
  const float4 g4 = ((const float4*)gam)[t];
  const float4 b4 = ((const float4*)bet)[t];
  const float o0 = (v.x - mean) * rstd * g4.x + b4.x;
  const float o1 = (v.y - mean) * rstd * g4.y + b4.y;
  const float o2 = (v.z - mean) * rstd * g4.z + b4.z;
  const float o3 = (v.w - mean) * rstd * g4.w + b4.w;
  if (OUTBF) {
    ushort4 o; o.x = f2bf(o0); o.y = f2bf(o1); o.z = f2bf(o2); o.w = f2bf(o3);
    ((ushort4*)outv)[row * 256 + t] = o;
  } else {
    ((float4*)outv)[row * 256 + t] = make_float4(o0, o1, o2, o3);
  }
}

// =====================================================================
extern "C" void kernel_launch(void* const* d_in, const int* in_sizes, int n_in,
                              void* d_out, int out_size, void* d_ws, size_t ws_size,
                              hipStream_t stream)
{
  const float* x   = (const float*)d_in[0];
  const float* Wq  = (const float*)d_in[1];
  const float* bq  = (const float*)d_in[2];
  const float* Wk  = (const float*)d_in[3];
  const float* bk  = (const float*)d_in[4];
  const float* Wv  = (const float*)d_in[5];
  const float* bv  = (const float*)d_in[6];
  const float* W1  = (const float*)d_in[7];
  const float* b1  = (const float*)d_in[8];
  const float* W2  = (const float*)d_in[9];
  const float* b2  = (const float*)d_in[10];
  const float* g1  = (const float*)d_in[11];
  const float* be1 = (const float*)d_in[12];
  const float* g2  = (const float*)d_in[13];
  const float* be2 = (const float*)d_in[14];

  // workspace (peak ~152 MiB), stream-ordered reuse:
  //  [0,32M)    xb (x bf16) -> vt (v^T bf16) after QKV
  //  [32,64M)   q -> ln1
  //  [64,96M)   k -> h[0:32M)   (h = FFN half-hidden, 64 MiB, M=16384 x N=2048)
  //  [96,128M)  v -> sc[0:32M) -> h[32:64M)
  //  [128,130M) sc tail (packed causal bf16, 34 MiB total from 96M)
  //  [130..152M) bf16 [N][K] weights: Wqkv(6M) | W1T(8M) | W2T(8M)
  char* ws = (char*)d_ws;
  u16*   xb    = (u16*)(ws);
  u16*   vt    = xb;
  u16*   qkv   = (u16*)(ws + 33554432);
  u16*   qbuf  = qkv;
  u16*   kbuf  = qkv + 16777216;
  u16*   vbuf  = qkv + 33554432;
  u16*   ln1   = qbuf;
  u16*   hbuf  = kbuf;                            // 64 MiB over k + v/sc-head
  u16*   sc    = (u16*)(ws + 100663296);
  u16*   wqkvT = (u16*)(ws + 136314880);
  u16*   w1T   = (u16*)(ws + 142606336);
  u16*   w2T   = (u16*)(ws + 150994944);
  float* attnf = (float*)d_out;

  const dim3 B256(256);

  // 1. x -> bf16
  cvt_f32_to_bf16<<<dim3(16384), B256, 0, stream>>>(x, xb, 16777216L);

  // 2. weight transposes: f32 [K][N] -> bf16 [N][K]
  transpose_bf16<0><<<dim3(32, 32, 1),  B256, 0, stream>>>(Wq, wqkvT,           1024, 1024, 0, 0);
  transpose_bf16<0><<<dim3(32, 32, 1),  B256, 0, stream>>>(Wk, wqkvT + 1048576, 1024, 1024, 0, 0);
  transpose_bf16<0><<<dim3(32, 32, 1),  B256, 0, stream>>>(Wv, wqkvT + 2097152, 1024, 1024, 0, 0);
  transpose_bf16<0><<<dim3(128, 32, 1), B256, 0, stream>>>(W1, w1T, 1024, 4096, 0, 0);
  transpose_bf16<0><<<dim3(32, 128, 1), B256, 0, stream>>>(W2, w2T, 4096, 1024, 0, 0);

  // 3. fused QKV: M=16384, N=3072, K=1024 (grid 24x128 = 3072 blocks)
  gemm_bt<0><<<dim3(24, 128), B256, 0, stream>>>(xb, 1024, 0, wqkvT, 1024, 0, qkv, 1024, 0,
                                                 bq, bk, bv, nullptr, 1024, 1.f);

  // 4. v -> v^T per batch, over dead xb
  transpose_bf16<1><<<dim3(32, 64, 8), B256, 0, stream>>>(vbuf, vt, 2048, 1024, 2097152, 2097152);

  // 5. scores = q@k^T/32 -> packed causal bf16 (all batches)
  gemm_bt<1><<<dim3(16, 16, 8), B256, 0, stream>>>(qbuf, 1024, 2097152, kbuf, 1024, 2097152,
                                                   sc, 0, 0, nullptr, nullptr, nullptr, nullptr,
                                                   1024, 0.03125f);

  // 6. row softmax in place on packed tiles (vectorized 16B load/store)
  softmax_packed<<<dim3(16384), B256, 0, stream>>>(sc);

  // 7. attn = probs @ v -> f32 into d_out (block-causal Keff)
  gemm_bt<2><<<dim3(8, 16, 8), B256, 0, stream>>>(sc, 0, 0, vt, 2048, 2097152,
                                                  attnf, 1024, 2097152, nullptr, nullptr, nullptr,
                                                  nullptr, 0, 1.f);

  // 8. LN1: d_out f32 -> ln1 bf16
  layernorm_k<1><<<dim3(16384), B256, 0, stream>>>(attnf, g1, be1, ln1);

  // 9. FFN split by N_ff into 2 halves of 2048:
  //    FFN1 half: 128x128 gemm_bt (M=16384, N=2048, K=1024; grid 16x128)
  //    FFN2 half: p8 256x256 at FULL FILL (M=16384, N=1024, K=2048; grid 256)
  for (int j = 0; j < 2; ++j) {
    const u16* w1h = w1T + (long)j * 2048 * 1024;
    gemm_bt<3><<<dim3(16, 128), B256, 0, stream>>>(ln1, 1024, 0, w1h, 1024, 0, hbuf, 2048, 0,
                                                   b1 + j * 2048, nullptr, nullptr, nullptr,
                                                   1024, 1.f);
    if (j == 0)
      gemm256_p8_ffn2<0><<<dim3(256), dim3(512), 0, stream>>>(hbuf, 2048, w2T, 4096,
                                                              (float*)d_out, 1024,
                                                              nullptr, nullptr, 2048, 4);
    else
      gemm256_p8_ffn2<1><<<dim3(256), dim3(512), 0, stream>>>(hbuf, 2048, w2T + 2048, 4096,
                                                              (float*)d_out, 1024,
                                                              b2, ln1, 2048, 4);
  }

  // 10. LN2 in place on d_out (f32)
  layernorm_k<0><<<dim3(16384), B256, 0, stream>>>((float*)d_out, g2, be2, d_out);
}

// Round 7
// 692.290 us; speedup vs baseline: 1.3230x; 1.0765x over previous
//
#include <hip/hip_runtime.h>
#include <cstdint>

#define DEV __device__ __forceinline__

typedef __attribute__((ext_vector_type(8))) short bf16x8;
typedef __attribute__((ext_vector_type(4))) float f32x4;
typedef unsigned short u16;
typedef unsigned int   u32;

// ---------- bf16 helpers (manual RNE) ----------
DEV u16 f2bf(float f) {
  u32 u = __float_as_uint(f);
  u = (u + 0x7FFFu + ((u >> 16) & 1u)) >> 16;
  return (u16)u;
}
DEV float bf2f(u16 s) { return __uint_as_float(((u32)s) << 16); }

// branch-free gelu via Abramowitz-Stegun 7.1.26 erf (|eps| <= 1.5e-7)
DEV float gelu_f(float x) {
  const float ax = fabsf(x) * 0.70710678118654752f;
  const float t = 1.f / fmaf(0.3275911f, ax, 1.f);
  float p = fmaf(1.061405429f, t, -1.453152027f);
  p = fmaf(p, t, 1.421413741f);
  p = fmaf(p, t, -0.284496736f);
  p = fmaf(p, t, 0.254829592f);
  p *= t;
  const float er = 1.f - p * __expf(-ax * ax);
  return 0.5f * x * (1.f + copysignf(er, x));
}

// ---------- async global->LDS (16B per lane) ----------
DEV void gload_lds16(const void* g, void* l) {
  typedef __attribute__((address_space(1))) const unsigned int GU;
  typedef __attribute__((address_space(3))) unsigned int LU;
  __builtin_amdgcn_global_load_lds((GU*)(uintptr_t)g, (LU*)(u32)(uintptr_t)l, 16, 0, 0);
}

// LDS byte swizzle for 256-tile kernel (conflict-free, R4-verified)
DEV int swz(int x) { return x ^ (((x >> 7) & 7) << 4); }

// packed causal score layout: per batch, 136 lower-triangle 128x128 tiles
#define BATCH_SC 2228224L   // u16 elements per batch (136*16384)

// =====================================================================
// gemm_bt 128x128 (m97 structure; 767 TF @K=1024 full-grid, R5-measured)
// MODE 0: fused QKV -> bf16 +bias (q/k/v split by gc>>10 into 32MB chunks)
// MODE 1: scores = q@k^T*scale -> packed causal bf16 tiles
// MODE 2: attn = probs(packed)@vt^T -> bf16, Keff=(mt+1)*128
// MODE 3: FFN1 -> bf16, +bias, gelu
// =====================================================================
template<int MODE>
__global__ __launch_bounds__(256, 4)
void gemm_bt(const u16* __restrict__ A, int lda, long abst,
             const u16* __restrict__ Bt, int ldb, long bbst,
             void* __restrict__ Cv, int ldc, long cbst,
             const float* __restrict__ bias,
             const float* __restrict__ bias2,
             const float* __restrict__ bias3,
             int K, float scale)
{
  const int nt = blockIdx.x, mt = blockIdx.y, bz = blockIdx.z;
  if (MODE == 1 && nt > mt) return;
  const int Keff = (MODE == 2) ? (mt + 1) * 128 : K;

  __shared__ u16 As[128 * 64];
  __shared__ u16 Bs[128 * 64];

  const int tid  = threadIdx.x;
  const int lane = tid & 63;
  const int wv   = tid >> 6;
  const int wr   = wv >> 1, wc = wv & 1;
  const int lrow = lane & 15;
  const int kgrp = lane >> 4;
  const int m0 = mt * 128, n0 = nt * 128;

  const int srow = tid >> 3;
  const int scol = (tid & 7) * 8;
  const u16* Ag;
  if (MODE == 2) {  // packed probs: chunk (k0>>7) at tri-offset, row stride 128
    Ag = A + bz * BATCH_SC + (long)(mt * (mt + 1) / 2) * 16384 + srow * 128 + scol;
  } else {
    Ag = A + (long)bz * abst + (long)(m0 + srow) * lda + scol;
  }
  const u16* Bg = Bt + (long)bz * bbst + (long)(n0 + srow) * ldb + scol;
  char* AsW = (char*)As + wv * 1024;
  char* BsW = (char*)Bs + wv * 1024;

  f32x4 acc[4][4];
#pragma unroll
  for (int mi = 0; mi < 4; ++mi)
#pragma unroll
    for (int ni = 0; ni < 4; ++ni)
#pragma unroll
      for (int e = 0; e < 4; ++e) acc[mi][ni][e] = 0.f;

  for (int k0 = 0; k0 < Keff; k0 += 64) {
#pragma unroll
    for (int i = 0; i < 4; ++i) {
      if (MODE == 2)
        gload_lds16(Ag + (long)(k0 >> 7) * 16384 + (k0 & 127) + i * 32 * 128, AsW + i * 4096);
      else
        gload_lds16(Ag + k0 + (long)i * 32 * lda, AsW + i * 4096);
      gload_lds16(Bg + k0 + (long)i * 32 * ldb, BsW + i * 4096);
    }
    __syncthreads();
#pragma unroll
    for (int kk = 0; kk < 2; ++kk) {
      const int kof = kk * 32 + kgrp * 8;
      bf16x8 af[4], bfr[4];
#pragma unroll
      for (int mi = 0; mi < 4; ++mi)
        af[mi] = *(const bf16x8*)&As[(wr * 64 + mi * 16 + lrow) * 64 + kof];
#pragma unroll
      for (int ni = 0; ni < 4; ++ni)
        bfr[ni] = *(const bf16x8*)&Bs[(wc * 64 + ni * 16 + lrow) * 64 + kof];
#pragma unroll
      for (int mi = 0; mi < 4; ++mi)
#pragma unroll
        for (int ni = 0; ni < 4; ++ni)
          acc[mi][ni] = __builtin_amdgcn_mfma_f32_16x16x32_bf16(af[mi], bfr[ni], acc[mi][ni], 0, 0, 0);
    }
    __syncthreads();
  }

  // epilogue: C/D layout col=lane&15, row=(lane>>4)*4+e [m89]
#pragma unroll
  for (int mi = 0; mi < 4; ++mi) {
#pragma unroll
    for (int ni = 0; ni < 4; ++ni) {
#pragma unroll
      for (int e = 0; e < 4; ++e) {
        const int rr = wr * 64 + mi * 16 + kgrp * 4 + e;
        const int cc = wc * 64 + ni * 16 + lrow;
        const int gr = m0 + rr, gc = n0 + cc;
        const float v = acc[mi][ni][e];
        if (MODE == 0) {
          const float bval = gc < 1024 ? bias[gc]
                              : (gc < 2048 ? bias2[gc & 1023] : bias3[gc & 1023]);
          ((u16*)Cv)[(long)(gc >> 10) * 16777216 + (long)gr * 1024 + (gc & 1023)]
              = f2bf(v + bval);
        } else if (MODE == 1) {
          ((u16*)Cv)[bz * BATCH_SC + (long)(mt * (mt + 1) / 2 + nt) * 16384 + rr * 128 + cc]
              = f2bf(v * scale);
        } else if (MODE == 2) {
          ((u16*)Cv)[(long)bz * cbst + (long)gr * ldc + gc] = f2bf(v);
        } else if (MODE == 3) {
          ((u16*)Cv)[(long)gr * ldc + gc] = f2bf(gelu_f(v + bias[gc]));
        }
      }
    }
  }
}

// =====================================================================
// gemm256_p8_ffn2: 8-phase counted-vmcnt 256x256 pipeline (T1-T5), FFN2.
// PASS 0: Cv = acc                 (fallback pass over K-half 0)
// PASS 1: Cv += acc + bias + resid (fallback pass over K-half 1)
// PASS 2: Cv  = acc + bias + resid (big-ws single pass, K=4096)
// =====================================================================
template<int PASS>
__global__ __launch_bounds__(512, 2)
void gemm256_p8_ffn2(const u16* __restrict__ A, int lda,
                     const u16* __restrict__ Bt, int ldb,
                     float* __restrict__ Cv, int ldc,
                     const float* __restrict__ bias,
                     const u16* __restrict__ resid,
                     int K, int NNT)
{
  __shared__ char smem[131072];
  const int tid  = threadIdx.x;
  const int lane = tid & 63;
  const int wv   = tid >> 6;
  const int wm   = wv >> 2, wn = wv & 3;
  const int lrow = lane & 15;
  const int kgrp = lane >> 4;

  const int nwg = gridDim.x;
  const int q0 = nwg >> 3, r = nwg & 7, xc = blockIdx.x & 7, pos = blockIdx.x >> 3;
  const int s = (xc < r ? xc * (q0 + 1) : r * (q0 + 1) + (xc - r) * q0) + pos;
  const int mt = s / NNT, nt = s % NNT;   // M-major: neighbors share A panel
  const int m0 = mt * 256, n0 = nt * 256;

  auto stageA = [&](int ktile, int dslot, int h) {
    int k0 = ktile << 6; const int kmax = K - 64; if (k0 > kmax) k0 = kmax;
#pragma unroll
    for (int j = 0; j < 2; ++j) {
      const int o = j * 8192 + tid * 16;
      const int l = swz(o);
      gload_lds16(A + (long)(m0 + h * 128 + (l >> 7)) * lda + k0 + ((l & 127) >> 1),
                  smem + dslot * 65536 + h * 16384 + o);
    }
  };
  auto stageB = [&](int ktile, int dslot, int h) {
    int k0 = ktile << 6; const int kmax = K - 64; if (k0 > kmax) k0 = kmax;
#pragma unroll
    for (int j = 0; j < 2; ++j) {
      const int o = j * 8192 + tid * 16;
      const int l = swz(o);
      gload_lds16(Bt + (long)(n0 + h * 128 + (l >> 7)) * ldb + k0 + ((l & 127) >> 1),
                  smem + dslot * 65536 + 32768 + h * 16384 + o);
    }
  };
  auto rdfrag = [&](int bofs, int row, int ks) -> bf16x8 {
    const int p = swz(row * 128 + ks * 64 + kgrp * 16);
    return *(const bf16x8*)(smem + bofs + p);
  };

  f32x4 acc[8][4];
#pragma unroll
  for (int mi = 0; mi < 8; ++mi)
#pragma unroll
    for (int ni = 0; ni < 4; ++ni)
#pragma unroll
      for (int e = 0; e < 4; ++e) acc[mi][ni][e] = 0.f;

  stageA(0, 0, 0); stageA(0, 0, 1); stageB(0, 0, 0); stageB(0, 0, 1);
  stageB(1, 1, 0); stageB(1, 1, 1);
  asm volatile("s_waitcnt vmcnt(4)" ::: "memory");
  __builtin_amdgcn_s_barrier();

  const int NI = K >> 7;
  bf16x8 bfrag[4][2], afrag[2][2];
  for (int i = 0; i < NI; ++i) {
    const int kp = 2 * i;
#pragma unroll
    for (int d = 0; d < 2; ++d) {
#pragma unroll
      for (int mq = 0; mq < 4; ++mq) {
        const int ph = d * 4 + mq;
        if (mq == 0) {
#pragma unroll
          for (int ni = 0; ni < 4; ++ni)
#pragma unroll
            for (int ks = 0; ks < 2; ++ks)
              bfrag[ni][ks] = rdfrag(d * 65536 + 32768, wn * 64 + ni * 16 + lrow, ks);
        }
#pragma unroll
        for (int mi2 = 0; mi2 < 2; ++mi2)
#pragma unroll
          for (int ks = 0; ks < 2; ++ks)
            afrag[mi2][ks] = rdfrag(d * 65536, wm * 128 + (2 * mq + mi2) * 16 + lrow, ks);
        switch (ph) {
          case 0: stageA(kp + 1, 1, 0); break;
          case 1: stageA(kp + 1, 1, 1); break;
          case 2: stageB(kp + 2, 0, 0); break;
          case 3: stageB(kp + 2, 0, 1); break;
          case 4: stageA(kp + 2, 0, 0); break;
          case 5: stageA(kp + 2, 0, 1); break;
          case 6: stageB(kp + 3, 1, 0); break;
          case 7: stageB(kp + 3, 1, 1); break;
        }
        __builtin_amdgcn_s_barrier();
        asm volatile("s_waitcnt lgkmcnt(0)" ::: "memory");
        __builtin_amdgcn_s_setprio(1);
#pragma unroll
        for (int mi2 = 0; mi2 < 2; ++mi2)
#pragma unroll
          for (int ni = 0; ni < 4; ++ni)
#pragma unroll
            for (int ks = 0; ks < 2; ++ks)
              acc[2 * mq + mi2][ni] = __builtin_amdgcn_mfma_f32_16x16x32_bf16(
                  afrag[mi2][ks], bfrag[ni][ks], acc[2 * mq + mi2][ni], 0, 0, 0);
        __builtin_amdgcn_s_setprio(0);
        if (mq == 3) asm volatile("s_waitcnt vmcnt(4)" ::: "memory");
        __builtin_amdgcn_s_barrier();
      }
    }
  }

#pragma unroll
  for (int mi = 0; mi < 8; ++mi) {
#pragma unroll
    for (int ni = 0; ni < 4; ++ni) {
      const int gc = n0 + wn * 64 + ni * 16 + lrow;
#pragma unroll
      for (int e = 0; e < 4; ++e) {
        const int gr = m0 + wm * 128 + mi * 16 + kgrp * 4 + e;
        if (PASS == 0) {
          Cv[(long)gr * ldc + gc] = acc[mi][ni][e];
        } else if (PASS == 1) {
          float* o = &Cv[(long)gr * ldc + gc];
          *o = *o + acc[mi][ni][e] + bias[gc] + bf2f(resid[(long)gr * 1024 + gc]);
        } else {
          Cv[(long)gr * ldc + gc] = acc[mi][ni][e] + bias[gc]
                                    + bf2f(resid[(long)gr * 1024 + gc]);
        }
      }
    }
  }
}

// ---------- transpose (+convert) to bf16 [C][R]; INBF: 0=f32, 1=bf16 ----------
template<int INBF>
__global__ __launch_bounds__(256)
void transpose_bf16(const void* __restrict__ inv, u16* __restrict__ out,
                    int R, int C, long ibst, long obst)
{
  __shared__ float t[32][33];
  const int bz = blockIdx.z;
  const int c0 = blockIdx.x * 32, r0 = blockIdx.y * 32;
  const int tx = threadIdx.x & 31, ty = threadIdx.x >> 5;
#pragma unroll
  for (int i = 0; i < 32; i += 8) {
    const long idx = (long)bz * ibst + (long)(r0 + ty + i) * C + (c0 + tx);
    t[ty + i][tx] = INBF ? bf2f(((const u16*)inv)[idx]) : ((const float*)inv)[idx];
  }
  __syncthreads();
#pragma unroll
  for (int i = 0; i < 32; i += 8)
    out[(long)bz * obst + (long)(c0 + ty + i) * R + (r0 + tx)] = f2bf(t[tx][ty + i]);
}

// ---------- f32 -> bf16 convert ----------
__global__ __launch_bounds__(256)
void cvt_f32_to_bf16(const float* __restrict__ in, u16* __restrict__ out, long n)
{
  const long idx = ((long)blockIdx.x * 256 + threadIdx.x) * 4;
  if (idx >= n) return;
  const float4 v = *(const float4*)(in + idx);
  ushort4 o;
  o.x = f2bf(v.x); o.y = f2bf(v.y); o.z = f2bf(v.z); o.w = f2bf(v.w);
  *(ushort4*)(out + idx) = o;
}

// ---------- causal row softmax on packed bf16 tiles, in place (16B vec) ----------
__global__ __launch_bounds__(256)
void softmax_packed(u16* __restrict__ sc)
{
  const int rowid = blockIdx.x;            // b*2048 + i
  const int b = rowid >> 11, i = rowid & 2047;
  const int mtt = i >> 7, rr = i & 127;
  u16* base = sc + (long)b * BATCH_SC + (long)(mtt * (mtt + 1) / 2) * 16384 + (long)rr * 128;
  const int t = threadIdx.x;
  const int lane = t & 63, wv = t >> 6;
  const int c   = t >> 4;
  const int off = (t & 15) * 8;
  const bool act = (c <= mtt);
  const int lim = (c < mtt) ? 8 : (c == mtt ? (rr - off + 1) : 0);
  u16* p = base + (long)c * 16384 + off;

  bf16x8 vv = {};
  if (act) vv = *(const bf16x8*)p;
  float vals[8];
  float m = -1e30f;
#pragma unroll
  for (int e = 0; e < 8; ++e) {
    vals[e] = (e < lim) ? bf2f((u16)vv[e]) : -1e30f;
    m = fmaxf(m, vals[e]);
  }
#pragma unroll
  for (int o = 1; o < 64; o <<= 1) m = fmaxf(m, __shfl_xor(m, o));
  __shared__ float rm[4], rsm[4];
  if (lane == 0) rm[wv] = m;
  __syncthreads();
  m = fmaxf(fmaxf(rm[0], rm[1]), fmaxf(rm[2], rm[3]));
  float pv[8];
  float ssum = 0.f;
#pragma unroll
  for (int e = 0; e < 8; ++e) { pv[e] = __expf(vals[e] - m); ssum += pv[e]; }
#pragma unroll
  for (int o = 1; o < 64; o <<= 1) ssum += __shfl_xor(ssum, o);
  if (lane == 0) rsm[wv] = ssum;
  __syncthreads();
  ssum = rsm[0] + rsm[1] + rsm[2] + rsm[3];
  const float inv = 1.f / ssum;
  if (act) {
    bf16x8 o;
#pragma unroll
    for (int e = 0; e < 8; ++e) o[e] = (short)f2bf(pv[e] * inv);
    *(bf16x8*)p = o;
  }
}

// ---------- LayerNorm rows of 1024; INBF/OUTBF: bf16 vs f32 ----------
template<int INBF, int OUTBF>
__global__ __launch_bounds__(256)
void layernorm_k(const void* __restrict__ in, const float* __restrict__ gam,
                 const float* __restrict__ bet, void* __restrict__ outv)
{
  const long row = blockIdx.x;
  const int t = threadIdx.x;
  const int lane = t & 63, wv = t >> 6;
  float v0, v1, v2, v3;
  if (INBF) {
    const ushort4 u = ((const ushort4*)in)[row * 256 + t];
    v0 = bf2f(u.x); v1 = bf2f(u.y); v2 = bf2f(u.z); v3 = bf2f(u.w);
  } else {
    const float4 v = ((const float4*)in)[row * 256 + t];
    v0 = v.x; v1 = v.y; v2 = v.z; v3 = v.w;
  }
  float s = v0 + v1 + v2 + v3;
  float q = v0 * v0 + v1 * v1 + v2 * v2 + v3 * v3;
#pragma unroll
  for (int o = 1; o < 64; o <<= 1) { s += __shfl_xor(s, o); q += __shfl_xor(q, o); }
  __shared__ float rs[4], rq[4];
  if (lane == 0) { rs[wv] = s; rq[wv] = q; }
  __syncthreads();
  s = rs[0] + rs[1] + rs[2] + rs[3];
  q = rq[0] + rq[1] + rq[2] + rq[3];
  const float mean = s * (1.f / 1024.f);
  const float var  = q * (1.f / 1024.f) - mean * mean;
  const float rstd = rsqrtf(var + 1e-5f);
  const float4 g4 = ((const float4*)gam)[t];
  const float4 b4 = ((const float4*)bet)[t];
  const float o0 = (v0 - mean) * rstd * g4.x + b4.x;
  const float o1 = (v1 - mean) * rstd * g4.y + b4.y;
  const float o2 = (v2 - mean) * rstd * g4.z + b4.z;
  const float o3 = (v3 - mean) * rstd * g4.w + b4.w;
  if (OUTBF) {
    ushort4 o; o.x = f2bf(o0); o.y = f2bf(o1); o.z = f2bf(o2); o.w = f2bf(o3);
    ((ushort4*)outv)[row * 256 + t] = o;
  } else {
    ((float4*)outv)[row * 256 + t] = make_float4(o0, o1, o2, o3);
  }
}

// =====================================================================
extern "C" void kernel_launch(void* const* d_in, const int* in_sizes, int n_in,
                              void* d_out, int out_size, void* d_ws, size_t ws_size,
                              hipStream_t stream)
{
  const float* x   = (const float*)d_in[0];
  const float* Wq  = (const float*)d_in[1];
  const float* bq  = (const float*)d_in[2];
  const float* Wk  = (const float*)d_in[3];
  const float* bk  = (const float*)d_in[4];
  const float* Wv  = (const float*)d_in[5];
  const float* bv  = (const float*)d_in[6];
  const float* W1  = (const float*)d_in[7];
  const float* b1  = (const float*)d_in[8];
  const float* W2  = (const float*)d_in[9];
  const float* b2  = (const float*)d_in[10];
  const float* g1  = (const float*)d_in[11];
  const float* be1 = (const float*)d_in[12];
  const float* g2  = (const float*)d_in[13];
  const float* be2 = (const float*)d_in[14];

  // workspace layout v3 (fallback peak 152 MiB; big-ws path peak 214 MiB):
  //  [0,22M)     weights bf16 [N][K]: wqkvT(6M) | w1T(8M) | w2T(8M)
  //  [22,54M)    xb (x bf16) -> vt (v^T) after QKV
  //  [54,86M)    q -> ln1 (after scores / LN1)
  //  [86,118M)   k -> pvout bf16 (PV out) -> h region start
  //  [118,150M)  v -> sc head (packed causal bf16, 35.7 MB -> [118,152M))
  //  h: big path [86,214M) full 128 MB; fallback [86,150M) 64 MB half
  char* ws = (char*)d_ws;
  u16*   wqkvT = (u16*)(ws);
  u16*   w1T   = (u16*)(ws + 6291456);
  u16*   w2T   = (u16*)(ws + 14680064);
  u16*   xb    = (u16*)(ws + 23068672);
  u16*   vt    = xb;
  u16*   qkv   = (u16*)(ws + 56623104);          // q|k|v contiguous 32MB chunks
  u16*   qbuf  = qkv;
  u16*   kbuf  = qkv + 16777216;
  u16*   vbuf  = qkv + 33554432;
  u16*   ln1   = qbuf;                            // over q
  u16*   pvout = kbuf;                            // PV out bf16, over k
  u16*   sc    = (u16*)(ws + 123731968);          // packed scores over v
  u16*   hbuf  = kbuf;                            // h region starts at 86M
  const bool big = (ws_size >= 224395264ULL);     // h full (128MB) fits?

  const dim3 B256(256);

  // 1. x -> bf16
  cvt_f32_to_bf16<<<dim3(16384), B256, 0, stream>>>(x, xb, 16777216L);

  // 2. weight transposes: f32 [K][N] -> bf16 [N][K]
  transpose_bf16<0><<<dim3(32, 32, 1),  B256, 0, stream>>>(Wq, wqkvT,           1024, 1024, 0, 0);
  transpose_bf16<0><<<dim3(32, 32, 1),  B256, 0, stream>>>(Wk, wqkvT + 1048576, 1024, 1024, 0, 0);
  transpose_bf16<0><<<dim3(32, 32, 1),  B256, 0, stream>>>(Wv, wqkvT + 2097152, 1024, 1024, 0, 0);
  transpose_bf16<0><<<dim3(128, 32, 1), B256, 0, stream>>>(W1, w1T, 1024, 4096, 0, 0);
  transpose_bf16<0><<<dim3(32, 128, 1), B256, 0, stream>>>(W2, w2T, 4096, 1024, 0, 0);

  // 3. fused QKV: M=16384, N=3072, K=1024 (grid 24x128)
  gemm_bt<0><<<dim3(24, 128), B256, 0, stream>>>(xb, 1024, 0, wqkvT, 1024, 0, qkv, 1024, 0,
                                                 bq, bk, bv, 1024, 1.f);

  // 4. v -> v^T per batch, over dead xb
  transpose_bf16<1><<<dim3(32, 64, 8), B256, 0, stream>>>(vbuf, vt, 2048, 1024, 2097152, 2097152);

  // 5. scores = q@k^T/32 -> packed causal bf16
  gemm_bt<1><<<dim3(16, 16, 8), B256, 0, stream>>>(qbuf, 1024, 2097152, kbuf, 1024, 2097152,
                                                   sc, 0, 0, nullptr, nullptr, nullptr,
                                                   1024, 0.03125f);

  // 6. row softmax in place
  softmax_packed<<<dim3(16384), B256, 0, stream>>>(sc);

  // 7. attn = probs @ v -> bf16 pvout (block-causal Keff)
  gemm_bt<2><<<dim3(8, 16, 8), B256, 0, stream>>>(sc, 0, 0, vt, 2048, 2097152,
                                                  pvout, 1024, 2097152, nullptr, nullptr, nullptr,
                                                  0, 1.f);

  // 8. LN1: pvout bf16 -> ln1 bf16
  layernorm_k<1, 1><<<dim3(16384), B256, 0, stream>>>(pvout, g1, be1, ln1);

  if (big) {
    // 9a. FFN1 single launch: M=16384, N=4096, K=1024 -> h [16384][4096] bf16
    gemm_bt<3><<<dim3(32, 128), B256, 0, stream>>>(ln1, 1024, 0, w1T, 1024, 0, hbuf, 4096, 0,
                                                   b1, nullptr, nullptr, 1024, 1.f);
    // 10a. FFN2 single p8: M=16384, N=1024, K=4096, grid 256 (full fill), 1 pass
    gemm256_p8_ffn2<2><<<dim3(256), dim3(512), 0, stream>>>(hbuf, 4096, w2T, 4096,
                                                            (float*)d_out, 1024,
                                                            b2, ln1, 4096, 4);
  } else {
    // 9b/10b. fallback: N_ff split in 2 halves of 2048 (h 64 MB reused)
    for (int j = 0; j < 2; ++j) {
      const u16* w1h = w1T + (long)j * 2048 * 1024;
      gemm_bt<3><<<dim3(16, 128), B256, 0, stream>>>(ln1, 1024, 0, w1h, 1024, 0, hbuf, 2048, 0,
                                                     b1 + j * 2048, nullptr, nullptr, 1024, 1.f);
      if (j == 0)
        gemm256_p8_ffn2<0><<<dim3(256), dim3(512), 0, stream>>>(hbuf, 2048, w2T, 4096,
                                                                (float*)d_out, 1024,
                                                                nullptr, nullptr, 2048, 4);
      else
        gemm256_p8_ffn2<1><<<dim3(256), dim3(512), 0, stream>>>(hbuf, 2048, w2T + 2048, 4096,
                                                                (float*)d_out, 1024,
                                                                b2, ln1, 2048, 4);
    }
  }

  // 11. LN2 in place on d_out (f32)
  layernorm_k<0, 0><<<dim3(16384), B256, 0, stream>>>(d_out, g2, be2, d_out);
}

// Round 8
// 663.722 us; speedup vs baseline: 1.3799x; 1.0430x over previous
//
#include <hip/hip_runtime.h>
#include <cstdint>

#define DEV __device__ __forceinline__

typedef __attribute__((ext_vector_type(8))) short bf16x8;
typedef __attribute__((ext_vector_type(4))) float f32x4;
typedef unsigned short u16;
typedef unsigned int   u32;

// ---------- bf16 helpers (manual RNE) ----------
DEV u16 f2bf(float f) {
  u32 u = __float_as_uint(f);
  u = (u + 0x7FFFu + ((u >> 16) & 1u)) >> 16;
  return (u16)u;
}
DEV float bf2f(u16 s) { return __uint_as_float(((u32)s) << 16); }

// gelu via tanh-form sigmoid: x * sigmoid(1.5957691x + 0.0713548x^3),
// constants pre-multiplied by -log2(e) for direct v_exp_f32 use.
// max abs error ~3e-4 (invisible at bf16). 7 VALU ops, branch-free.
DEV float gelu_f(float x) {
  const float x2 = x * x;
  const float z  = x * fmaf(-0.1029436f, x2, -2.3022082f);   // -2y*log2e
  const float e  = exp2f(z);                                  // e^{-2y}
  return x * (1.f / (1.f + e));                               // x*sigmoid(2y)
}

// ---------- async global->LDS (16B per lane) ----------
DEV void gload_lds16(const void* g, void* l) {
  typedef __attribute__((address_space(1))) const unsigned int GU;
  typedef __attribute__((address_space(3))) unsigned int LU;
  __builtin_amdgcn_global_load_lds((GU*)(uintptr_t)g, (LU*)(u32)(uintptr_t)l, 16, 0, 0);
}

// LDS byte swizzle for 256-tile kernel (conflict-free, R4-verified)
DEV int swz(int x) { return x ^ (((x >> 7) & 7) << 4); }

// packed causal score layout: per batch, 136 lower-triangle 128x128 tiles
#define BATCH_SC 2228224L   // u16 elements per batch (136*16384)

// =====================================================================
// gemm_bt 128x128 (m97 structure; 767 TF @K=1024 full-grid, R5-measured)
// MODE 0: fused QKV -> bf16 +bias (q/k/v split by gc>>10 into 32MB chunks)
// MODE 1: scores = q@k^T*scale -> packed causal bf16 tiles
// MODE 2: attn = probs(packed)@vt^T -> bf16, Keff=(mt+1)*128
// MODE 3: FFN1 -> bf16, +bias, gelu
// =====================================================================
template<int MODE>
__global__ __launch_bounds__(256, 4)
void gemm_bt(const u16* __restrict__ A, int lda, long abst,
             const u16* __restrict__ Bt, int ldb, long bbst,
             void* __restrict__ Cv, int ldc, long cbst,
             const float* __restrict__ bias,
             const float* __restrict__ bias2,
             const float* __restrict__ bias3,
             int K, float scale)
{
  const int nt = blockIdx.x, mt = blockIdx.y, bz = blockIdx.z;
  if (MODE == 1 && nt > mt) return;
  const int Keff = (MODE == 2) ? (mt + 1) * 128 : K;

  __shared__ u16 As[128 * 64];
  __shared__ u16 Bs[128 * 64];

  const int tid  = threadIdx.x;
  const int lane = tid & 63;
  const int wv   = tid >> 6;
  const int wr   = wv >> 1, wc = wv & 1;
  const int lrow = lane & 15;
  const int kgrp = lane >> 4;
  const int m0 = mt * 128, n0 = nt * 128;

  const int srow = tid >> 3;
  const int scol = (tid & 7) * 8;
  const u16* Ag;
  if (MODE == 2) {  // packed probs: chunk (k0>>7) at tri-offset, row stride 128
    Ag = A + bz * BATCH_SC + (long)(mt * (mt + 1) / 2) * 16384 + srow * 128 + scol;
  } else {
    Ag = A + (long)bz * abst + (long)(m0 + srow) * lda + scol;
  }
  const u16* Bg = Bt + (long)bz * bbst + (long)(n0 + srow) * ldb + scol;
  char* AsW = (char*)As + wv * 1024;
  char* BsW = (char*)Bs + wv * 1024;

  f32x4 acc[4][4];
#pragma unroll
  for (int mi = 0; mi < 4; ++mi)
#pragma unroll
    for (int ni = 0; ni < 4; ++ni)
#pragma unroll
      for (int e = 0; e < 4; ++e) acc[mi][ni][e] = 0.f;

  for (int k0 = 0; k0 < Keff; k0 += 64) {
#pragma unroll
    for (int i = 0; i < 4; ++i) {
      if (MODE == 2)
        gload_lds16(Ag + (long)(k0 >> 7) * 16384 + (k0 & 127) + i * 32 * 128, AsW + i * 4096);
      else
        gload_lds16(Ag + k0 + (long)i * 32 * lda, AsW + i * 4096);
      gload_lds16(Bg + k0 + (long)i * 32 * ldb, BsW + i * 4096);
    }
    __syncthreads();
#pragma unroll
    for (int kk = 0; kk < 2; ++kk) {
      const int kof = kk * 32 + kgrp * 8;
      bf16x8 af[4], bfr[4];
#pragma unroll
      for (int mi = 0; mi < 4; ++mi)
        af[mi] = *(const bf16x8*)&As[(wr * 64 + mi * 16 + lrow) * 64 + kof];
#pragma unroll
      for (int ni = 0; ni < 4; ++ni)
        bfr[ni] = *(const bf16x8*)&Bs[(wc * 64 + ni * 16 + lrow) * 64 + kof];
#pragma unroll
      for (int mi = 0; mi < 4; ++mi)
#pragma unroll
        for (int ni = 0; ni < 4; ++ni)
          acc[mi][ni] = __builtin_amdgcn_mfma_f32_16x16x32_bf16(af[mi], bfr[ni], acc[mi][ni], 0, 0, 0);
    }
    __syncthreads();
  }

  // epilogue: C/D layout col=lane&15, row=(lane>>4)*4+e [m89]
#pragma unroll
  for (int mi = 0; mi < 4; ++mi) {
#pragma unroll
    for (int ni = 0; ni < 4; ++ni) {
#pragma unroll
      for (int e = 0; e < 4; ++e) {
        const int rr = wr * 64 + mi * 16 + kgrp * 4 + e;
        const int cc = wc * 64 + ni * 16 + lrow;
        const int gr = m0 + rr, gc = n0 + cc;
        const float v = acc[mi][ni][e];
        if (MODE == 0) {
          const float bval = gc < 1024 ? bias[gc]
                              : (gc < 2048 ? bias2[gc & 1023] : bias3[gc & 1023]);
          ((u16*)Cv)[(long)(gc >> 10) * 16777216 + (long)gr * 1024 + (gc & 1023)]
              = f2bf(v + bval);
        } else if (MODE == 1) {
          ((u16*)Cv)[bz * BATCH_SC + (long)(mt * (mt + 1) / 2 + nt) * 16384 + rr * 128 + cc]
              = f2bf(v * scale);
        } else if (MODE == 2) {
          ((u16*)Cv)[(long)bz * cbst + (long)gr * ldc + gc] = f2bf(v);
        } else if (MODE == 3) {
          ((u16*)Cv)[(long)gr * ldc + gc] = f2bf(gelu_f(v + bias[gc]));
        }
      }
    }
  }
}

// =====================================================================
// gemm256_p8_ffn2: 8-phase counted-vmcnt 256x256 pipeline (T1-T5), FFN2.
// PASS 0: f32 Cv = acc                 (fallback K-half 0)
// PASS 1: f32 Cv += acc + bias + resid (fallback K-half 1)
// PASS 2: bf16 Cv = acc + bias + resid (big-ws single pass, K=4096)
// =====================================================================
template<int PASS>
__global__ __launch_bounds__(512, 2)
void gemm256_p8_ffn2(const u16* __restrict__ A, int lda,
                     const u16* __restrict__ Bt, int ldb,
                     void* __restrict__ Cv, int ldc,
                     const float* __restrict__ bias,
                     const u16* __restrict__ resid,
                     int K, int NNT)
{
  __shared__ char smem[131072];
  const int tid  = threadIdx.x;
  const int lane = tid & 63;
  const int wv   = tid >> 6;
  const int wm   = wv >> 2, wn = wv & 3;
  const int lrow = lane & 15;
  const int kgrp = lane >> 4;

  const int nwg = gridDim.x;
  const int q0 = nwg >> 3, r = nwg & 7, xc = blockIdx.x & 7, pos = blockIdx.x >> 3;
  const int s = (xc < r ? xc * (q0 + 1) : r * (q0 + 1) + (xc - r) * q0) + pos;
  const int mt = s / NNT, nt = s % NNT;   // M-major: neighbors share A panel
  const int m0 = mt * 256, n0 = nt * 256;

  auto stageA = [&](int ktile, int dslot, int h) {
    int k0 = ktile << 6; const int kmax = K - 64; if (k0 > kmax) k0 = kmax;
#pragma unroll
    for (int j = 0; j < 2; ++j) {
      const int o = j * 8192 + tid * 16;
      const int l = swz(o);
      gload_lds16(A + (long)(m0 + h * 128 + (l >> 7)) * lda + k0 + ((l & 127) >> 1),
                  smem + dslot * 65536 + h * 16384 + o);
    }
  };
  auto stageB = [&](int ktile, int dslot, int h) {
    int k0 = ktile << 6; const int kmax = K - 64; if (k0 > kmax) k0 = kmax;
#pragma unroll
    for (int j = 0; j < 2; ++j) {
      const int o = j * 8192 + tid * 16;
      const int l = swz(o);
      gload_lds16(Bt + (long)(n0 + h * 128 + (l >> 7)) * ldb + k0 + ((l & 127) >> 1),
                  smem + dslot * 65536 + 32768 + h * 16384 + o);
    }
  };
  auto rdfrag = [&](int bofs, int row, int ks) -> bf16x8 {
    const int p = swz(row * 128 + ks * 64 + kgrp * 16);
    return *(const bf16x8*)(smem + bofs + p);
  };

  f32x4 acc[8][4];
#pragma unroll
  for (int mi = 0; mi < 8; ++mi)
#pragma unroll
    for (int ni = 0; ni < 4; ++ni)
#pragma unroll
      for (int e = 0; e < 4; ++e) acc[mi][ni][e] = 0.f;

  stageA(0, 0, 0); stageA(0, 0, 1); stageB(0, 0, 0); stageB(0, 0, 1);
  stageB(1, 1, 0); stageB(1, 1, 1);
  asm volatile("s_waitcnt vmcnt(4)" ::: "memory");
  __builtin_amdgcn_s_barrier();

  const int NI = K >> 7;
  bf16x8 bfrag[4][2], afrag[2][2];
  for (int i = 0; i < NI; ++i) {
    const int kp = 2 * i;
#pragma unroll
    for (int d = 0; d < 2; ++d) {
#pragma unroll
      for (int mq = 0; mq < 4; ++mq) {
        const int ph = d * 4 + mq;
        if (mq == 0) {
#pragma unroll
          for (int ni = 0; ni < 4; ++ni)
#pragma unroll
            for (int ks = 0; ks < 2; ++ks)
              bfrag[ni][ks] = rdfrag(d * 65536 + 32768, wn * 64 + ni * 16 + lrow, ks);
        }
#pragma unroll
        for (int mi2 = 0; mi2 < 2; ++mi2)
#pragma unroll
          for (int ks = 0; ks < 2; ++ks)
            afrag[mi2][ks] = rdfrag(d * 65536, wm * 128 + (2 * mq + mi2) * 16 + lrow, ks);
        switch (ph) {
          case 0: stageA(kp + 1, 1, 0); break;
          case 1: stageA(kp + 1, 1, 1); break;
          case 2: stageB(kp + 2, 0, 0); break;
          case 3: stageB(kp + 2, 0, 1); break;
          case 4: stageA(kp + 2, 0, 0); break;
          case 5: stageA(kp + 2, 0, 1); break;
          case 6: stageB(kp + 3, 1, 0); break;
          case 7: stageB(kp + 3, 1, 1); break;
        }
        __builtin_amdgcn_s_barrier();
        asm volatile("s_waitcnt lgkmcnt(0)" ::: "memory");
        __builtin_amdgcn_s_setprio(1);
#pragma unroll
        for (int mi2 = 0; mi2 < 2; ++mi2)
#pragma unroll
          for (int ni = 0; ni < 4; ++ni)
#pragma unroll
            for (int ks = 0; ks < 2; ++ks)
              acc[2 * mq + mi2][ni] = __builtin_amdgcn_mfma_f32_16x16x32_bf16(
                  afrag[mi2][ks], bfrag[ni][ks], acc[2 * mq + mi2][ni], 0, 0, 0);
        __builtin_amdgcn_s_setprio(0);
        if (mq == 3) asm volatile("s_waitcnt vmcnt(4)" ::: "memory");
        __builtin_amdgcn_s_barrier();
      }
    }
  }

#pragma unroll
  for (int mi = 0; mi < 8; ++mi) {
#pragma unroll
    for (int ni = 0; ni < 4; ++ni) {
      const int gc = n0 + wn * 64 + ni * 16 + lrow;
#pragma unroll
      for (int e = 0; e < 4; ++e) {
        const int gr = m0 + wm * 128 + mi * 16 + kgrp * 4 + e;
        if (PASS == 0) {
          ((float*)Cv)[(long)gr * ldc + gc] = acc[mi][ni][e];
        } else if (PASS == 1) {
          float* o = &((float*)Cv)[(long)gr * ldc + gc];
          *o = *o + acc[mi][ni][e] + bias[gc] + bf2f(resid[(long)gr * 1024 + gc]);
        } else {
          ((u16*)Cv)[(long)gr * ldc + gc]
              = f2bf(acc[mi][ni][e] + bias[gc] + bf2f(resid[(long)gr * 1024 + gc]));
        }
      }
    }
  }
}

// ---------- all weight transposes in ONE launch: f32 [R][C] -> bf16 [C][R] ----------
__global__ __launch_bounds__(256)
void prep_weights(const float* __restrict__ Wq, const float* __restrict__ Wk,
                  const float* __restrict__ Wv, const float* __restrict__ W1,
                  const float* __restrict__ W2,
                  u16* __restrict__ wqkvT, u16* __restrict__ w1T, u16* __restrict__ w2T)
{
  const int idx = blockIdx.x;
  const float* in; u16* out; int R, C, cx0, ry0;
  if (idx < 3072) {
    in = (idx < 1024) ? Wq : (idx < 2048 ? Wk : Wv);
    out = wqkvT + (long)(idx >> 10) * 1048576;
    const int i = idx & 1023; cx0 = (i & 31) * 32; ry0 = (i >> 5) * 32; R = 1024; C = 1024;
  } else if (idx < 7168) {
    const int i = idx - 3072; in = W1; out = w1T; R = 1024; C = 4096;
    cx0 = (i & 127) * 32; ry0 = (i >> 7) * 32;
  } else {
    const int i = idx - 7168; in = W2; out = w2T; R = 4096; C = 1024;
    cx0 = (i & 31) * 32; ry0 = (i >> 5) * 32;
  }
  __shared__ float t[32][33];
  const int tx = threadIdx.x & 31, ty = threadIdx.x >> 5;
#pragma unroll
  for (int i = 0; i < 32; i += 8)
    t[ty + i][tx] = in[(long)(ry0 + ty + i) * C + (cx0 + tx)];
  __syncthreads();
#pragma unroll
  for (int i = 0; i < 32; i += 8)
    out[(long)(cx0 + ty + i) * R + (ry0 + tx)] = f2bf(t[tx][ty + i]);
}

// ---------- transpose bf16 [R][C] -> bf16 [C][R] (v^T), batched ----------
__global__ __launch_bounds__(256)
void transpose_v(const u16* __restrict__ inv, u16* __restrict__ out,
                 int R, int C, long ibst, long obst)
{
  __shared__ float t[32][33];
  const int bz = blockIdx.z;
  const int c0 = blockIdx.x * 32, r0 = blockIdx.y * 32;
  const int tx = threadIdx.x & 31, ty = threadIdx.x >> 5;
#pragma unroll
  for (int i = 0; i < 32; i += 8) {
    const long idx = (long)bz * ibst + (long)(r0 + ty + i) * C + (c0 + tx);
    t[ty + i][tx] = bf2f(inv[idx]);
  }
  __syncthreads();
#pragma unroll
  for (int i = 0; i < 32; i += 8)
    out[(long)bz * obst + (long)(c0 + ty + i) * R + (r0 + tx)] = f2bf(t[tx][ty + i]);
}

// ---------- f32 -> bf16 convert ----------
__global__ __launch_bounds__(256)
void cvt_f32_to_bf16(const float* __restrict__ in, u16* __restrict__ out, long n)
{
  const long idx = ((long)blockIdx.x * 256 + threadIdx.x) * 4;
  if (idx >= n) return;
  const float4 v = *(const float4*)(in + idx);
  ushort4 o;
  o.x = f2bf(v.x); o.y = f2bf(v.y); o.z = f2bf(v.z); o.w = f2bf(v.w);
  *(ushort4*)(out + idx) = o;
}

// ---------- causal row softmax on packed bf16 tiles, in place (16B vec) ----------
__global__ __launch_bounds__(256)
void softmax_packed(u16* __restrict__ sc)
{
  const int rowid = blockIdx.x;            // b*2048 + i
  const int b = rowid >> 11, i = rowid & 2047;
  const int mtt = i >> 7, rr = i & 127;
  u16* base = sc + (long)b * BATCH_SC + (long)(mtt * (mtt + 1) / 2) * 16384 + (long)rr * 128;
  const int t = threadIdx.x;
  const int lane = t & 63, wv = t >> 6;
  const int c   = t >> 4;
  const int off = (t & 15) * 8;
  const bool act = (c <= mtt);
  const int lim = (c < mtt) ? 8 : (c == mtt ? (rr - off + 1) : 0);
  u16* p = base + (long)c * 16384 + off;

  bf16x8 vv = {};
  if (act) vv = *(const bf16x8*)p;
  float vals[8];
  float m = -1e30f;
#pragma unroll
  for (int e = 0; e < 8; ++e) {
    vals[e] = (e < lim) ? bf2f((u16)vv[e]) : -1e30f;
    m = fmaxf(m, vals[e]);
  }
#pragma unroll
  for (int o = 1; o < 64; o <<= 1) m = fmaxf(m, __shfl_xor(m, o));
  __shared__ float rm[4], rsm[4];
  if (lane == 0) rm[wv] = m;
  __syncthreads();
  m = fmaxf(fmaxf(rm[0], rm[1]), fmaxf(rm[2], rm[3]));
  float pv[8];
  float ssum = 0.f;
#pragma unroll
  for (int e = 0; e < 8; ++e) { pv[e] = __expf(vals[e] - m); ssum += pv[e]; }
#pragma unroll
  for (int o = 1; o < 64; o <<= 1) ssum += __shfl_xor(ssum, o);
  if (lane == 0) rsm[wv] = ssum;
  __syncthreads();
  ssum = rsm[0] + rsm[1] + rsm[2] + rsm[3];
  const float inv = 1.f / ssum;
  if (act) {
    bf16x8 o;
#pragma unroll
    for (int e = 0; e < 8; ++e) o[e] = (short)f2bf(pv[e] * inv);
    *(bf16x8*)p = o;
  }
}

// ---------- LayerNorm rows of 1024; INBF/OUTBF: bf16 vs f32 ----------
template<int INBF, int OUTBF>
__global__ __launch_bounds__(256)
void layernorm_k(const void* __restrict__ in, const float* __restrict__ gam,
                 const float* __restrict__ bet, void* __restrict__ outv)
{
  const long row = blockIdx.x;
  const int t = threadIdx.x;
  const int lane = t & 63, wv = t >> 6;
  float v0, v1, v2, v3;
  if (INBF) {
    const ushort4 u = ((const ushort4*)in)[row * 256 + t];
    v0 = bf2f(u.x); v1 = bf2f(u.y); v2 = bf2f(u.z); v3 = bf2f(u.w);
  } else {
    const float4 v = ((const float4*)in)[row * 256 + t];
    v0 = v.x; v1 = v.y; v2 = v.z; v3 = v.w;
  }
  float s = v0 + v1 + v2 + v3;
  float q = v0 * v0 + v1 * v1 + v2 * v2 + v3 * v3;
#pragma unroll
  for (int o = 1; o < 64; o <<= 1) { s += __shfl_xor(s, o); q += __shfl_xor(q, o); }
  __shared__ float rs[4], rq[4];
  if (lane == 0) { rs[wv] = s; rq[wv] = q; }
  __syncthreads();
  s = rs[0] + rs[1] + rs[2] + rs[3];
  q = rq[0] + rq[1] + rq[2] + rq[3];
  const float mean = s * (1.f / 1024.f);
  const float var  = q * (1.f / 1024.f) - mean * mean;
  const float rstd = rsqrtf(var + 1e-5f);
  const float4 g4 = ((const float4*)gam)[t];
  const float4 b4 = ((const float4*)bet)[t];
  const float o0 = (v0 - mean) * rstd * g4.x + b4.x;
  const float o1 = (v1 - mean) * rstd * g4.y + b4.y;
  const float o2 = (v2 - mean) * rstd * g4.z + b4.z;
  const float o3 = (v3 - mean) * rstd * g4.w + b4.w;
  if (OUTBF) {
    ushort4 o; o.x = f2bf(o0); o.y = f2bf(o1); o.z = f2bf(o2); o.w = f2bf(o3);
    ((ushort4*)outv)[row * 256 + t] = o;
  } else {
    ((float4*)outv)[row * 256 + t] = make_float4(o0, o1, o2, o3);
  }
}

// =====================================================================
extern "C" void kernel_launch(void* const* d_in, const int* in_sizes, int n_in,
                              void* d_out, int out_size, void* d_ws, size_t ws_size,
                              hipStream_t stream)
{
  const float* x   = (const float*)d_in[0];
  const float* Wq  = (const float*)d_in[1];
  const float* bq  = (const float*)d_in[2];
  const float* Wk  = (const float*)d_in[3];
  const float* bk  = (const float*)d_in[4];
  const float* Wv  = (const float*)d_in[5];
  const float* bv  = (const float*)d_in[6];
  const float* W1  = (const float*)d_in[7];
  const float* b1  = (const float*)d_in[8];
  const float* W2  = (const float*)d_in[9];
  const float* b2  = (const float*)d_in[10];
  const float* g1  = (const float*)d_in[11];
  const float* be1 = (const float*)d_in[12];
  const float* g2  = (const float*)d_in[13];
  const float* be2 = (const float*)d_in[14];

  // workspace layout (fallback peak 152 MiB; big path peak 214 MiB):
  //  [0,22M)     weights bf16 [N][K]: wqkvT(6M) | w1T(8M) | w2T(8M)
  //  [22,54M)    xb (x bf16) -> vt (v^T) -> ffn2out bf16 (big path)
  //  [54,86M)    q -> ln1
  //  [86,118M)   k -> pvout bf16 -> h region start
  //  [118,152M)  v -> sc (packed causal bf16, 35.7 MB)
  //  h: big path [86,214M) full 128 MB; fallback [86,150M) 64 MB half
  char* ws = (char*)d_ws;
  u16*   wqkvT = (u16*)(ws);
  u16*   w1T   = (u16*)(ws + 6291456);
  u16*   w2T   = (u16*)(ws + 14680064);
  u16*   xb    = (u16*)(ws + 23068672);
  u16*   vt    = xb;
  u16*   f2out = xb;                              // FFN2 bf16 out (big path), over vt
  u16*   qkv   = (u16*)(ws + 56623104);
  u16*   qbuf  = qkv;
  u16*   kbuf  = qkv + 16777216;
  u16*   vbuf  = qkv + 33554432;
  u16*   ln1   = qbuf;
  u16*   pvout = kbuf;
  u16*   sc    = (u16*)(ws + 123731968);
  u16*   hbuf  = kbuf;                            // h region starts at 86M
  const bool big = (ws_size >= 224395264ULL);

  const dim3 B256(256);

  // 1. x -> bf16
  cvt_f32_to_bf16<<<dim3(16384), B256, 0, stream>>>(x, xb, 16777216L);

  // 2. all weight transposes, one launch (11264 tiles)
  prep_weights<<<dim3(11264), B256, 0, stream>>>(Wq, Wk, Wv, W1, W2, wqkvT, w1T, w2T);

  // 3. fused QKV: M=16384, N=3072, K=1024 (grid 24x128)
  gemm_bt<0><<<dim3(24, 128), B256, 0, stream>>>(xb, 1024, 0, wqkvT, 1024, 0, qkv, 1024, 0,
                                                 bq, bk, bv, 1024, 1.f);

  // 4. v -> v^T per batch, over dead xb
  transpose_v<<<dim3(32, 64, 8), B256, 0, stream>>>(vbuf, vt, 2048, 1024, 2097152, 2097152);

  // 5. scores = q@k^T/32 -> packed causal bf16
  gemm_bt<1><<<dim3(16, 16, 8), B256, 0, stream>>>(qbuf, 1024, 2097152, kbuf, 1024, 2097152,
                                                   sc, 0, 0, nullptr, nullptr, nullptr,
                                                   1024, 0.03125f);

  // 6. row softmax in place
  softmax_packed<<<dim3(16384), B256, 0, stream>>>(sc);

  // 7. attn = probs @ v -> bf16 pvout (block-causal Keff)
  gemm_bt<2><<<dim3(8, 16, 8), B256, 0, stream>>>(sc, 0, 0, vt, 2048, 2097152,
                                                  pvout, 1024, 2097152, nullptr, nullptr, nullptr,
                                                  0, 1.f);

  // 8. LN1: pvout bf16 -> ln1 bf16
  layernorm_k<1, 1><<<dim3(16384), B256, 0, stream>>>(pvout, g1, be1, ln1);

  if (big) {
    // 9a. FFN1 single launch: M=16384, N=4096, K=1024 -> h bf16
    gemm_bt<3><<<dim3(32, 128), B256, 0, stream>>>(ln1, 1024, 0, w1T, 1024, 0, hbuf, 4096, 0,
                                                   b1, nullptr, nullptr, 1024, 1.f);
    // 10a. FFN2 single p8: M=16384, N=1024, K=4096, grid 256, bf16 out (vt dead)
    gemm256_p8_ffn2<2><<<dim3(256), dim3(512), 0, stream>>>(hbuf, 4096, w2T, 4096,
                                                            f2out, 1024, b2, ln1, 4096, 4);
    // 11a. LN2: f2out bf16 -> d_out f32
    layernorm_k<1, 0><<<dim3(16384), B256, 0, stream>>>(f2out, g2, be2, d_out);
  } else {
    // 9b/10b. fallback: N_ff split in 2 halves of 2048 (h 64 MB reused)
    for (int j = 0; j < 2; ++j) {
      const u16* w1h = w1T + (long)j * 2048 * 1024;
      gemm_bt<3><<<dim3(16, 128), B256, 0, stream>>>(ln1, 1024, 0, w1h, 1024, 0, hbuf, 2048, 0,
                                                     b1 + j * 2048, nullptr, nullptr, 1024, 1.f);
      if (j == 0)
        gemm256_p8_ffn2<0><<<dim3(256), dim3(512), 0, stream>>>(hbuf, 2048, w2T, 4096,
                                                                d_out, 1024,
                                                                nullptr, nullptr, 2048, 4);
      else
        gemm256_p8_ffn2<1><<<dim3(256), dim3(512), 0, stream>>>(hbuf, 2048, w2T + 2048, 4096,
                                                                d_out, 1024,
                                                                b2, ln1, 2048, 4);
    }
    // 11b. LN2 in place on d_out (f32)
    layernorm_k<0, 0><<<dim3(16384), B256, 0, stream>>>(d_out, g2, be2, d_out);
  }
}

// Round 9
// 648.257 us; speedup vs baseline: 1.4128x; 1.0239x over previous
//
#include <hip/hip_runtime.h>
#include <cstdint>

#define DEV __device__ __forceinline__

typedef __attribute__((ext_vector_type(8))) short bf16x8;
typedef __attribute__((ext_vector_type(4))) float f32x4;
typedef unsigned short u16;
typedef unsigned int   u32;

// ---------- bf16 helpers (manual RNE) ----------
DEV u16 f2bf(float f) {
  u32 u = __float_as_uint(f);
  u = (u + 0x7FFFu + ((u >> 16) & 1u)) >> 16;
  return (u16)u;
}
DEV float bf2f(u16 s) { return __uint_as_float(((u32)s) << 16); }

// gelu via tanh-form sigmoid, 7 VALU ops, max abs err ~3e-4
DEV float gelu_f(float x) {
  const float x2 = x * x;
  const float z  = x * fmaf(-0.1029436f, x2, -2.3022082f);
  const float e  = exp2f(z);
  return x * (1.f / (1.f + e));
}

// ---------- async global->LDS (16B per lane) ----------
DEV void gload_lds16(const void* g, void* l) {
  typedef __attribute__((address_space(1))) const unsigned int GU;
  typedef __attribute__((address_space(3))) unsigned int LU;
  __builtin_amdgcn_global_load_lds((GU*)(uintptr_t)g, (LU*)(u32)(uintptr_t)l, 16, 0, 0);
}

// LDS byte swizzle for 256-tile kernel (conflict-free, R4-verified)
DEV int swz(int x) { return x ^ (((x >> 7) & 7) << 4); }

// packed causal score layout: per batch, 136 lower-triangle 128x128 tiles
#define BATCH_SC 2228224L   // u16 elements per batch (136*16384)

// =====================================================================
// gemm_bt 128x128 (m97 structure; 767 TF @K=1024 full-grid, R5-measured)
// SWZ=1: T2 bank-conflict swizzle (both-sides: permuted global source col
//        + XOR'd read slot; LDS dest stays linear for global_load_lds).
//        A/B experiment: FFN1 swizzled, QKV/scores/PV control.
// MODE 0: fused QKV -> bf16 +bias (q/k/v split by gc>>10 into 32MB chunks)
// MODE 1: scores = q@k^T*scale -> packed causal bf16 tiles
// MODE 2: attn = probs(packed)@vt^T -> bf16, Keff=(mt+1)*128
// MODE 3: FFN1 -> bf16, +bias, gelu
// =====================================================================
template<int MODE, int SWZ>
__global__ __launch_bounds__(256, 4)
void gemm_bt(const u16* __restrict__ A, int lda, long abst,
             const u16* __restrict__ Bt, int ldb, long bbst,
             void* __restrict__ Cv, int ldc, long cbst,
             const float* __restrict__ bias,
             const float* __restrict__ bias2,
             const float* __restrict__ bias3,
             int K, float scale)
{
  const int nt = blockIdx.x, mt = blockIdx.y, bz = blockIdx.z;
  if (MODE == 1 && nt > mt) return;
  const int Keff = (MODE == 2) ? (mt + 1) * 128 : K;

  __shared__ u16 As[128 * 64];
  __shared__ u16 Bs[128 * 64];

  const int tid  = threadIdx.x;
  const int lane = tid & 63;
  const int wv   = tid >> 6;
  const int wr   = wv >> 1, wc = wv & 1;
  const int lrow = lane & 15;
  const int kgrp = lane >> 4;
  const int m0 = mt * 128, n0 = nt * 128;

  const int srow = tid >> 3;                    // staging row 0..31 (per 32-row chunk)
  // staging col byte; SWZ: inverse-permuted source so swizzled READ sees (r,c)
  const int scolb = ((tid & 7) * 16) ^ (SWZ ? ((srow & 7) << 4) : 0);
  const u16* Ag;
  if (MODE == 2) {  // packed probs: chunk (k0>>7) at tri-offset, row stride 128
    Ag = A + bz * BATCH_SC + (long)(mt * (mt + 1) / 2) * 16384 + srow * 128 + (scolb >> 1);
  } else {
    Ag = A + (long)bz * abst + (long)(m0 + srow) * lda + (scolb >> 1);
  }
  const u16* Bg = Bt + (long)bz * bbst + (long)(n0 + srow) * ldb + (scolb >> 1);
  char* AsW = (char*)As + wv * 1024;            // wave-uniform linear LDS dest
  char* BsW = (char*)Bs + wv * 1024;

  f32x4 acc[4][4];
#pragma unroll
  for (int mi = 0; mi < 4; ++mi)
#pragma unroll
    for (int ni = 0; ni < 4; ++ni)
#pragma unroll
      for (int e = 0; e < 4; ++e) acc[mi][ni][e] = 0.f;

  for (int k0 = 0; k0 < Keff; k0 += 64) {
#pragma unroll
    for (int i = 0; i < 4; ++i) {
      if (MODE == 2)
        gload_lds16(Ag + (long)(k0 >> 7) * 16384 + (k0 & 127) + i * 32 * 128, AsW + i * 4096);
      else
        gload_lds16(Ag + k0 + (long)i * 32 * lda, AsW + i * 4096);
      gload_lds16(Bg + k0 + (long)i * 32 * ldb, BsW + i * 4096);
    }
    __syncthreads();
#pragma unroll
    for (int kk = 0; kk < 2; ++kk) {
      // read byte offset within row; SWZ XORs the 16B slot with row bits 0-2
      const int kofb  = kk * 64 + kgrp * 16;
      const int kofbs = kofb ^ (SWZ ? ((lrow & 7) << 4) : 0);
      bf16x8 af[4], bfr[4];
#pragma unroll
      for (int mi = 0; mi < 4; ++mi)
        af[mi] = *(const bf16x8*)((const char*)As + (wr * 64 + mi * 16 + lrow) * 128 + kofbs);
#pragma unroll
      for (int ni = 0; ni < 4; ++ni)
        bfr[ni] = *(const bf16x8*)((const char*)Bs + (wc * 64 + ni * 16 + lrow) * 128 + kofbs);
#pragma unroll
      for (int mi = 0; mi < 4; ++mi)
#pragma unroll
        for (int ni = 0; ni < 4; ++ni)
          acc[mi][ni] = __builtin_amdgcn_mfma_f32_16x16x32_bf16(af[mi], bfr[ni], acc[mi][ni], 0, 0, 0);
    }
    __syncthreads();
  }

  // epilogue: C/D layout col=lane&15, row=(lane>>4)*4+e [m89]
#pragma unroll
  for (int mi = 0; mi < 4; ++mi) {
#pragma unroll
    for (int ni = 0; ni < 4; ++ni) {
#pragma unroll
      for (int e = 0; e < 4; ++e) {
        const int rr = wr * 64 + mi * 16 + kgrp * 4 + e;
        const int cc = wc * 64 + ni * 16 + lrow;
        const int gr = m0 + rr, gc = n0 + cc;
        const float v = acc[mi][ni][e];
        if (MODE == 0) {
          const float bval = gc < 1024 ? bias[gc]
                              : (gc < 2048 ? bias2[gc & 1023] : bias3[gc & 1023]);
          ((u16*)Cv)[(long)(gc >> 10) * 16777216 + (long)gr * 1024 + (gc & 1023)]
              = f2bf(v + bval);
        } else if (MODE == 1) {
          ((u16*)Cv)[bz * BATCH_SC + (long)(mt * (mt + 1) / 2 + nt) * 16384 + rr * 128 + cc]
              = f2bf(v * scale);
        } else if (MODE == 2) {
          ((u16*)Cv)[(long)bz * cbst + (long)gr * ldc + gc] = f2bf(v);
        } else if (MODE == 3) {
          ((u16*)Cv)[(long)gr * ldc + gc] = f2bf(gelu_f(v + bias[gc]));
        }
      }
    }
  }
}

// =====================================================================
// gemm256_p8_ffn2: 8-phase counted-vmcnt 256x256 pipeline (T1-T5), FFN2.
// PASS 0: f32 Cv = acc                 (fallback K-half 0)
// PASS 1: f32 Cv += acc + bias + resid (fallback K-half 1)
// PASS 2: bf16 Cv = acc + bias + resid (big-ws single pass, K=4096)
// =====================================================================
template<int PASS>
__global__ __launch_bounds__(512, 2)
void gemm256_p8_ffn2(const u16* __restrict__ A, int lda,
                     const u16* __restrict__ Bt, int ldb,
                     void* __restrict__ Cv, int ldc,
                     const float* __restrict__ bias,
                     const u16* __restrict__ resid,
                     int K, int NNT)
{
  __shared__ char smem[131072];
  const int tid  = threadIdx.x;
  const int lane = tid & 63;
  const int wv   = tid >> 6;
  const int wm   = wv >> 2, wn = wv & 3;
  const int lrow = lane & 15;
  const int kgrp = lane >> 4;

  const int nwg = gridDim.x;
  const int q0 = nwg >> 3, r = nwg & 7, xc = blockIdx.x & 7, pos = blockIdx.x >> 3;
  const int s = (xc < r ? xc * (q0 + 1) : r * (q0 + 1) + (xc - r) * q0) + pos;
  const int mt = s / NNT, nt = s % NNT;   // M-major: neighbors share A panel
  const int m0 = mt * 256, n0 = nt * 256;

  auto stageA = [&](int ktile, int dslot, int h) {
    int k0 = ktile << 6; const int kmax = K - 64; if (k0 > kmax) k0 = kmax;
#pragma unroll
    for (int j = 0; j < 2; ++j) {
      const int o = j * 8192 + tid * 16;
      const int l = swz(o);
      gload_lds16(A + (long)(m0 + h * 128 + (l >> 7)) * lda + k0 + ((l & 127) >> 1),
                  smem + dslot * 65536 + h * 16384 + o);
    }
  };
  auto stageB = [&](int ktile, int dslot, int h) {
    int k0 = ktile << 6; const int kmax = K - 64; if (k0 > kmax) k0 = kmax;
#pragma unroll
    for (int j = 0; j < 2; ++j) {
      const int o = j * 8192 + tid * 16;
      const int l = swz(o);
      gload_lds16(Bt + (long)(n0 + h * 128 + (l >> 7)) * ldb + k0 + ((l & 127) >> 1),
                  smem + dslot * 65536 + 32768 + h * 16384 + o);
    }
  };
  auto rdfrag = [&](int bofs, int row, int ks) -> bf16x8 {
    const int p = swz(row * 128 + ks * 64 + kgrp * 16);
    return *(const bf16x8*)(smem + bofs + p);
  };

  f32x4 acc[8][4];
#pragma unroll
  for (int mi = 0; mi < 8; ++mi)
#pragma unroll
    for (int ni = 0; ni < 4; ++ni)
#pragma unroll
      for (int e = 0; e < 4; ++e) acc[mi][ni][e] = 0.f;

  stageA(0, 0, 0); stageA(0, 0, 1); stageB(0, 0, 0); stageB(0, 0, 1);
  stageB(1, 1, 0); stageB(1, 1, 1);
  asm volatile("s_waitcnt vmcnt(4)" ::: "memory");
  __builtin_amdgcn_s_barrier();

  const int NI = K >> 7;
  bf16x8 bfrag[4][2], afrag[2][2];
  for (int i = 0; i < NI; ++i) {
    const int kp = 2 * i;
#pragma unroll
    for (int d = 0; d < 2; ++d) {
#pragma unroll
      for (int mq = 0; mq < 4; ++mq) {
        const int ph = d * 4 + mq;
        if (mq == 0) {
#pragma unroll
          for (int ni = 0; ni < 4; ++ni)
#pragma unroll
            for (int ks = 0; ks < 2; ++ks)
              bfrag[ni][ks] = rdfrag(d * 65536 + 32768, wn * 64 + ni * 16 + lrow, ks);
        }
#pragma unroll
        for (int mi2 = 0; mi2 < 2; ++mi2)
#pragma unroll
          for (int ks = 0; ks < 2; ++ks)
            afrag[mi2][ks] = rdfrag(d * 65536, wm * 128 + (2 * mq + mi2) * 16 + lrow, ks);
        switch (ph) {
          case 0: stageA(kp + 1, 1, 0); break;
          case 1: stageA(kp + 1, 1, 1); break;
          case 2: stageB(kp + 2, 0, 0); break;
          case 3: stageB(kp + 2, 0, 1); break;
          case 4: stageA(kp + 2, 0, 0); break;
          case 5: stageA(kp + 2, 0, 1); break;
          case 6: stageB(kp + 3, 1, 0); break;
          case 7: stageB(kp + 3, 1, 1); break;
        }
        __builtin_amdgcn_s_barrier();
        asm volatile("s_waitcnt lgkmcnt(0)" ::: "memory");
        __builtin_amdgcn_s_setprio(1);
#pragma unroll
        for (int mi2 = 0; mi2 < 2; ++mi2)
#pragma unroll
          for (int ni = 0; ni < 4; ++ni)
#pragma unroll
            for (int ks = 0; ks < 2; ++ks)
              acc[2 * mq + mi2][ni] = __builtin_amdgcn_mfma_f32_16x16x32_bf16(
                  afrag[mi2][ks], bfrag[ni][ks], acc[2 * mq + mi2][ni], 0, 0, 0);
        __builtin_amdgcn_s_setprio(0);
        if (mq == 3) asm volatile("s_waitcnt vmcnt(4)" ::: "memory");
        __builtin_amdgcn_s_barrier();
      }
    }
  }

#pragma unroll
  for (int mi = 0; mi < 8; ++mi) {
#pragma unroll
    for (int ni = 0; ni < 4; ++ni) {
      const int gc = n0 + wn * 64 + ni * 16 + lrow;
#pragma unroll
      for (int e = 0; e < 4; ++e) {
        const int gr = m0 + wm * 128 + mi * 16 + kgrp * 4 + e;
        if (PASS == 0) {
          ((float*)Cv)[(long)gr * ldc + gc] = acc[mi][ni][e];
        } else if (PASS == 1) {
          float* o = &((float*)Cv)[(long)gr * ldc + gc];
          *o = *o + acc[mi][ni][e] + bias[gc] + bf2f(resid[(long)gr * 1024 + gc]);
        } else {
          ((u16*)Cv)[(long)gr * ldc + gc]
              = f2bf(acc[mi][ni][e] + bias[gc] + bf2f(resid[(long)gr * 1024 + gc]));
        }
      }
    }
  }
}

// ---------- all weight transposes in ONE launch: f32 [R][C] -> bf16 [C][R] ----------
__global__ __launch_bounds__(256)
void prep_weights(const float* __restrict__ Wq, const float* __restrict__ Wk,
                  const float* __restrict__ Wv, const float* __restrict__ W1,
                  const float* __restrict__ W2,
                  u16* __restrict__ wqkvT, u16* __restrict__ w1T, u16* __restrict__ w2T)
{
  const int idx = blockIdx.x;
  const float* in; u16* out; int R, C, cx0, ry0;
  if (idx < 3072) {
    in = (idx < 1024) ? Wq : (idx < 2048 ? Wk : Wv);
    out = wqkvT + (long)(idx >> 10) * 1048576;
    const int i = idx & 1023; cx0 = (i & 31) * 32; ry0 = (i >> 5) * 32; R = 1024; C = 1024;
  } else if (idx < 7168) {
    const int i = idx - 3072; in = W1; out = w1T; R = 1024; C = 4096;
    cx0 = (i & 127) * 32; ry0 = (i >> 7) * 32;
  } else {
    const int i = idx - 7168; in = W2; out = w2T; R = 4096; C = 1024;
    cx0 = (i & 31) * 32; ry0 = (i >> 5) * 32;
  }
  __shared__ float t[32][33];
  const int tx = threadIdx.x & 31, ty = threadIdx.x >> 5;
#pragma unroll
  for (int i = 0; i < 32; i += 8)
    t[ty + i][tx] = in[(long)(ry0 + ty + i) * C + (cx0 + tx)];
  __syncthreads();
#pragma unroll
  for (int i = 0; i < 32; i += 8)
    out[(long)(cx0 + ty + i) * R + (ry0 + tx)] = f2bf(t[tx][ty + i]);
}

// ---------- transpose bf16 [R][C] -> bf16 [C][R] (v^T), batched ----------
__global__ __launch_bounds__(256)
void transpose_v(const u16* __restrict__ inv, u16* __restrict__ out,
                 int R, int C, long ibst, long obst)
{
  __shared__ float t[32][33];
  const int bz = blockIdx.z;
  const int c0 = blockIdx.x * 32, r0 = blockIdx.y * 32;
  const int tx = threadIdx.x & 31, ty = threadIdx.x >> 5;
#pragma unroll
  for (int i = 0; i < 32; i += 8) {
    const long idx = (long)bz * ibst + (long)(r0 + ty + i) * C + (c0 + tx);
    t[ty + i][tx] = bf2f(inv[idx]);
  }
  __syncthreads();
#pragma unroll
  for (int i = 0; i < 32; i += 8)
    out[(long)bz * obst + (long)(c0 + ty + i) * R + (r0 + tx)] = f2bf(t[tx][ty + i]);
}

// ---------- f32 -> bf16 convert ----------
__global__ __launch_bounds__(256)
void cvt_f32_to_bf16(const float* __restrict__ in, u16* __restrict__ out, long n)
{
  const long idx = ((long)blockIdx.x * 256 + threadIdx.x) * 4;
  if (idx >= n) return;
  const float4 v = *(const float4*)(in + idx);
  ushort4 o;
  o.x = f2bf(v.x); o.y = f2bf(v.y); o.z = f2bf(v.z); o.w = f2bf(v.w);
  *(ushort4*)(out + idx) = o;
}

// ---------- causal row softmax on packed bf16 tiles, in place (16B vec) ----------
__global__ __launch_bounds__(256)
void softmax_packed(u16* __restrict__ sc)
{
  const int rowid = blockIdx.x;            // b*2048 + i
  const int b = rowid >> 11, i = rowid & 2047;
  const int mtt = i >> 7, rr = i & 127;
  u16* base = sc + (long)b * BATCH_SC + (long)(mtt * (mtt + 1) / 2) * 16384 + (long)rr * 128;
  const int t = threadIdx.x;
  const int lane = t & 63, wv = t >> 6;
  const int c   = t >> 4;
  const int off = (t & 15) * 8;
  const bool act = (c <= mtt);
  const int lim = (c < mtt) ? 8 : (c == mtt ? (rr - off + 1) : 0);
  u16* p = base + (long)c * 16384 + off;

  bf16x8 vv = {};
  if (act) vv = *(const bf16x8*)p;
  float vals[8];
  float m = -1e30f;
#pragma unroll
  for (int e = 0; e < 8; ++e) {
    vals[e] = (e < lim) ? bf2f((u16)vv[e]) : -1e30f;
    m = fmaxf(m, vals[e]);
  }
#pragma unroll
  for (int o = 1; o < 64; o <<= 1) m = fmaxf(m, __shfl_xor(m, o));
  __shared__ float rm[4], rsm[4];
  if (lane == 0) rm[wv] = m;
  __syncthreads();
  m = fmaxf(fmaxf(rm[0], rm[1]), fmaxf(rm[2], rm[3]));
  float pv[8];
  float ssum = 0.f;
#pragma unroll
  for (int e = 0; e < 8; ++e) { pv[e] = __expf(vals[e] - m); ssum += pv[e]; }
#pragma unroll
  for (int o = 1; o < 64; o <<= 1) ssum += __shfl_xor(ssum, o);
  if (lane == 0) rsm[wv] = ssum;
  __syncthreads();
  ssum = rsm[0] + rsm[1] + rsm[2] + rsm[3];
  const float inv = 1.f / ssum;
  if (act) {
    bf16x8 o;
#pragma unroll
    for (int e = 0; e < 8; ++e) o[e] = (short)f2bf(pv[e] * inv);
    *(bf16x8*)p = o;
  }
}

// ---------- LayerNorm rows of 1024; INBF/OUTBF: bf16 vs f32 ----------
template<int INBF, int OUTBF>
__global__ __launch_bounds__(256)
void layernorm_k(const void* __restrict__ in, const float* __restrict__ gam,
                 const float* __restrict__ bet, void* __restrict__ outv)
{
  const long row = blockIdx.x;
  const int t = threadIdx.x;
  const int lane = t & 63, wv = t >> 6;
  float v0, v1, v2, v3;
  if (INBF) {
    const ushort4 u = ((const ushort4*)in)[row * 256 + t];
    v0 = bf2f(u.x); v1 = bf2f(u.y); v2 = bf2f(u.z); v3 = bf2f(u.w);
  } else {
    const float4 v = ((const float4*)in)[row * 256 + t];
    v0 = v.x; v1 = v.y; v2 = v.z; v3 = v.w;
  }
  float s = v0 + v1 + v2 + v3;
  float q = v0 * v0 + v1 * v1 + v2 * v2 + v3 * v3;
#pragma unroll
  for (int o = 1; o < 64; o <<= 1) { s += __shfl_xor(s, o); q += __shfl_xor(q, o); }
  __shared__ float rs[4], rq[4];
  if (lane == 0) { rs[wv] = s; rq[wv] = q; }
  __syncthreads();
  s = rs[0] + rs[1] + rs[2] + rs[3];
  q = rq[0] + rq[1] + rq[2] + rq[3];
  const float mean = s * (1.f / 1024.f);
  const float var  = q * (1.f / 1024.f) - mean * mean;
  const float rstd = rsqrtf(var + 1e-5f);
  const float4 g4 = ((const float4*)gam)[t];
  const float4 b4 = ((const float4*)bet)[t];
  const float o0 = (v0 - mean) * rstd * g4.x + b4.x;
  const float o1 = (v1 - mean) * rstd * g4.y + b4.y;
  const float o2 = (v2 - mean) * rstd * g4.z + b4.z;
  const float o3 = (v3 - mean) * rstd * g4.w + b4.w;
  if (OUTBF) {
    ushort4 o; o.x = f2bf(o0); o.y = f2bf(o1); o.z = f2bf(o2); o.w = f2bf(o3);
    ((ushort4*)outv)[row * 256 + t] = o;
  } else {
    ((float4*)outv)[row * 256 + t] = make_float4(o0, o1, o2, o3);
  }
}

// =====================================================================
extern "C" void kernel_launch(void* const* d_in, const int* in_sizes, int n_in,
                              void* d_out, int out_size, void* d_ws, size_t ws_size,
                              hipStream_t stream)
{
  const float* x   = (const float*)d_in[0];
  const float* Wq  = (const float*)d_in[1];
  const float* bq  = (const float*)d_in[2];
  const float* Wk  = (const float*)d_in[3];
  const float* bk  = (const float*)d_in[4];
  const float* Wv  = (const float*)d_in[5];
  const float* bv  = (const float*)d_in[6];
  const float* W1  = (const float*)d_in[7];
  const float* b1  = (const float*)d_in[8];
  const float* W2  = (const float*)d_in[9];
  const float* b2  = (const float*)d_in[10];
  const float* g1  = (const float*)d_in[11];
  const float* be1 = (const float*)d_in[12];
  const float* g2  = (const float*)d_in[13];
  const float* be2 = (const float*)d_in[14];

  // workspace layout (fallback peak 152 MiB; big path peak 214 MiB):
  //  [0,22M)     weights bf16 [N][K]: wqkvT(6M) | w1T(8M) | w2T(8M)
  //  [22,54M)    xb (x bf16) -> vt (v^T) -> ffn2out bf16 (big path)
  //  [54,86M)    q -> ln1
  //  [86,118M)   k -> pvout bf16 -> h region start
  //  [118,152M)  v -> sc (packed causal bf16, 35.7 MB)
  //  h: big path [86,214M) full 128 MB; fallback [86,150M) 64 MB half
  char* ws = (char*)d_ws;
  u16*   wqkvT = (u16*)(ws);
  u16*   w1T   = (u16*)(ws + 6291456);
  u16*   w2T   = (u16*)(ws + 14680064);
  u16*   xb    = (u16*)(ws + 23068672);
  u16*   vt    = xb;
  u16*   f2out = xb;                              // FFN2 bf16 out (big path), over vt
  u16*   qkv   = (u16*)(ws + 56623104);
  u16*   qbuf  = qkv;
  u16*   kbuf  = qkv + 16777216;
  u16*   vbuf  = qkv + 33554432;
  u16*   ln1   = qbuf;
  u16*   pvout = kbuf;
  u16*   sc    = (u16*)(ws + 123731968);
  u16*   hbuf  = kbuf;                            // h region starts at 86M
  const bool big = (ws_size >= 224395264ULL);

  const dim3 B256(256);

  // 1. x -> bf16
  cvt_f32_to_bf16<<<dim3(16384), B256, 0, stream>>>(x, xb, 16777216L);

  // 2. all weight transposes, one launch (11264 tiles)
  prep_weights<<<dim3(11264), B256, 0, stream>>>(Wq, Wk, Wv, W1, W2, wqkvT, w1T, w2T);

  // 3. fused QKV: M=16384, N=3072, K=1024 (grid 24x128) — SWZ=0 control arm
  gemm_bt<0, 0><<<dim3(24, 128), B256, 0, stream>>>(xb, 1024, 0, wqkvT, 1024, 0, qkv, 1024, 0,
                                                    bq, bk, bv, 1024, 1.f);

  // 4. v -> v^T per batch, over dead xb
  transpose_v<<<dim3(32, 64, 8), B256, 0, stream>>>(vbuf, vt, 2048, 1024, 2097152, 2097152);

  // 5. scores = q@k^T/32 -> packed causal bf16
  gemm_bt<1, 0><<<dim3(16, 16, 8), B256, 0, stream>>>(qbuf, 1024, 2097152, kbuf, 1024, 2097152,
                                                      sc, 0, 0, nullptr, nullptr, nullptr,
                                                      1024, 0.03125f);

  // 6. row softmax in place
  softmax_packed<<<dim3(16384), B256, 0, stream>>>(sc);

  // 7. attn = probs @ v -> bf16 pvout (block-causal Keff)
  gemm_bt<2, 0><<<dim3(8, 16, 8), B256, 0, stream>>>(sc, 0, 0, vt, 2048, 2097152,
                                                     pvout, 1024, 2097152, nullptr, nullptr,
                                                     nullptr, 0, 1.f);

  // 8. LN1: pvout bf16 -> ln1 bf16
  layernorm_k<1, 1><<<dim3(16384), B256, 0, stream>>>(pvout, g1, be1, ln1);

  if (big) {
    // 9a. FFN1 single launch — SWZ=1 test arm (T2 bank-conflict fix)
    gemm_bt<3, 1><<<dim3(32, 128), B256, 0, stream>>>(ln1, 1024, 0, w1T, 1024, 0, hbuf, 4096, 0,
                                                      b1, nullptr, nullptr, 1024, 1.f);
    // 10a. FFN2 single p8: M=16384, N=1024, K=4096, grid 256, bf16 out (vt dead)
    gemm256_p8_ffn2<2><<<dim3(256), dim3(512), 0, stream>>>(hbuf, 4096, w2T, 4096,
                                                            f2out, 1024, b2, ln1, 4096, 4);
    // 11a. LN2: f2out bf16 -> d_out f32
    layernorm_k<1, 0><<<dim3(16384), B256, 0, stream>>>(f2out, g2, be2, d_out);
  } else {
    // 9b/10b. fallback: N_ff split in 2 halves of 2048 (h 64 MB reused)
    for (int j = 0; j < 2; ++j) {
      const u16* w1h = w1T + (long)j * 2048 * 1024;
      gemm_bt<3, 1><<<dim3(16, 128), B256, 0, stream>>>(ln1, 1024, 0, w1h, 1024, 0, hbuf, 2048, 0,
                                                        b1 + j * 2048, nullptr, nullptr,
                                                        1024, 1.f);
      if (j == 0)
        gemm256_p8_ffn2<0><<<dim3(256), dim3(512), 0, stream>>>(hbuf, 2048, w2T, 4096,
                                                                d_out, 1024,
                                                                nullptr, nullptr, 2048, 4);
      else
        gemm256_p8_ffn2<1><<<dim3(256), dim3(512), 0, stream>>>(hbuf, 2048, w2T + 2048, 4096,
                                                                d_out, 1024,
                                                                b2, ln1, 2048, 4);
    }
    // 11b. LN2 in place on d_out (f32)
    layernorm_k<0, 0><<<dim3(16384), B256, 0, stream>>>(d_out, g2, be2, d_out);
  }
}

// Round 10
// 611.647 us; speedup vs baseline: 1.4974x; 1.0599x over previous
//
#include <hip/hip_runtime.h>
#include <cstdint>

#define DEV __device__ __forceinline__

typedef __attribute__((ext_vector_type(8))) short bf16x8;
typedef __attribute__((ext_vector_type(4))) float f32x4;
typedef unsigned short u16;
typedef unsigned int   u32;

// ---------- bf16 helpers (manual RNE) ----------
DEV u16 f2bf(float f) {
  u32 u = __float_as_uint(f);
  u = (u + 0x7FFFu + ((u >> 16) & 1u)) >> 16;
  return (u16)u;
}
DEV float bf2f(u16 s) { return __uint_as_float(((u32)s) << 16); }

// gelu via tanh-form sigmoid, 7 VALU ops, max abs err ~3e-4
DEV float gelu_f(float x) {
  const float x2 = x * x;
  const float z  = x * fmaf(-0.1029436f, x2, -2.3022082f);
  const float e  = exp2f(z);
  return x * (1.f / (1.f + e));
}

// ---------- async global->LDS (16B per lane) ----------
DEV void gload_lds16(const void* g, void* l) {
  typedef __attribute__((address_space(1))) const unsigned int GU;
  typedef __attribute__((address_space(3))) unsigned int LU;
  __builtin_amdgcn_global_load_lds((GU*)(uintptr_t)g, (LU*)(u32)(uintptr_t)l, 16, 0, 0);
}

// LDS byte swizzle for 256-tile kernel (conflict-free, R4-verified)
DEV int swz(int x) { return x ^ (((x >> 7) & 7) << 4); }

// packed causal score layout: per batch, 136 lower-triangle 128x128 tiles
#define BATCH_SC 2228224L   // u16 elements per batch (136*16384)

// =====================================================================
// gemm_bt 128x128 (m97 structure + T2 swizzle; R9 A/B: conflicts 5e7->0,
// FFN1 202->172 us = 799 TF at 4 blocks/CU)
// T2 both-sides: linear gload_lds dest + inverse-permuted global source
// column + XOR'd read slot (byte ^ (row&7)<<4 within the 128B row).
// MODE 0: fused QKV -> bf16 +bias (q/k/v split by gc>>10 into 32MB chunks)
// MODE 1: scores = q@k^T*scale -> packed causal bf16 tiles
// MODE 2: attn = probs(packed)@vt^T -> bf16, Keff=(mt+1)*128
// MODE 3: FFN1 -> bf16, +bias, gelu
// =====================================================================
template<int MODE>
__global__ __launch_bounds__(256, 4)
void gemm_bt(const u16* __restrict__ A, int lda, long abst,
             const u16* __restrict__ Bt, int ldb, long bbst,
             void* __restrict__ Cv, int ldc, long cbst,
             const float* __restrict__ bias,
             const float* __restrict__ bias2,
             const float* __restrict__ bias3,
             int K, float scale)
{
  const int nt = blockIdx.x, mt = blockIdx.y, bz = blockIdx.z;
  if (MODE == 1 && nt > mt) return;
  const int Keff = (MODE == 2) ? (mt + 1) * 128 : K;

  __shared__ u16 As[128 * 64];
  __shared__ u16 Bs[128 * 64];

  const int tid  = threadIdx.x;
  const int lane = tid & 63;
  const int wv   = tid >> 6;
  const int wr   = wv >> 1, wc = wv & 1;
  const int lrow = lane & 15;
  const int kgrp = lane >> 4;
  const int m0 = mt * 128, n0 = nt * 128;

  const int srow = tid >> 3;                    // staging row 0..31 (per 32-row chunk)
  // inverse-permuted source col byte so the swizzled READ sees (row, col)
  const int scolb = ((tid & 7) * 16) ^ ((srow & 7) << 4);
  const u16* Ag;
  if (MODE == 2) {  // packed probs: chunk (k0>>7) at tri-offset, row stride 128
    Ag = A + bz * BATCH_SC + (long)(mt * (mt + 1) / 2) * 16384 + srow * 128 + (scolb >> 1);
  } else {
    Ag = A + (long)bz * abst + (long)(m0 + srow) * lda + (scolb >> 1);
  }
  const u16* Bg = Bt + (long)bz * bbst + (long)(n0 + srow) * ldb + (scolb >> 1);
  char* AsW = (char*)As + wv * 1024;            // wave-uniform linear LDS dest
  char* BsW = (char*)Bs + wv * 1024;

  f32x4 acc[4][4];
#pragma unroll
  for (int mi = 0; mi < 4; ++mi)
#pragma unroll
    for (int ni = 0; ni < 4; ++ni)
#pragma unroll
      for (int e = 0; e < 4; ++e) acc[mi][ni][e] = 0.f;

  for (int k0 = 0; k0 < Keff; k0 += 64) {
#pragma unroll
    for (int i = 0; i < 4; ++i) {
      if (MODE == 2)
        gload_lds16(Ag + (long)(k0 >> 7) * 16384 + (k0 & 127) + i * 32 * 128, AsW + i * 4096);
      else
        gload_lds16(Ag + k0 + (long)i * 32 * lda, AsW + i * 4096);
      gload_lds16(Bg + k0 + (long)i * 32 * ldb, BsW + i * 4096);
    }
    __syncthreads();
#pragma unroll
    for (int kk = 0; kk < 2; ++kk) {
      // read byte offset within row, 16B slot XOR'd with row bits 0-2 (T2)
      const int kofb = (kk * 64 + kgrp * 16) ^ ((lrow & 7) << 4);
      bf16x8 af[4], bfr[4];
#pragma unroll
      for (int mi = 0; mi < 4; ++mi)
        af[mi] = *(const bf16x8*)((const char*)As + (wr * 64 + mi * 16 + lrow) * 128 + kofb);
#pragma unroll
      for (int ni = 0; ni < 4; ++ni)
        bfr[ni] = *(const bf16x8*)((const char*)Bs + (wc * 64 + ni * 16 + lrow) * 128 + kofb);
#pragma unroll
      for (int mi = 0; mi < 4; ++mi)
#pragma unroll
        for (int ni = 0; ni < 4; ++ni)
          acc[mi][ni] = __builtin_amdgcn_mfma_f32_16x16x32_bf16(af[mi], bfr[ni], acc[mi][ni], 0, 0, 0);
    }
    __syncthreads();
  }

  // epilogue: C/D layout col=lane&15, row=(lane>>4)*4+e [m89]
#pragma unroll
  for (int mi = 0; mi < 4; ++mi) {
#pragma unroll
    for (int ni = 0; ni < 4; ++ni) {
#pragma unroll
      for (int e = 0; e < 4; ++e) {
        const int rr = wr * 64 + mi * 16 + kgrp * 4 + e;
        const int cc = wc * 64 + ni * 16 + lrow;
        const int gr = m0 + rr, gc = n0 + cc;
        const float v = acc[mi][ni][e];
        if (MODE == 0) {
          const float bval = gc < 1024 ? bias[gc]
                              : (gc < 2048 ? bias2[gc & 1023] : bias3[gc & 1023]);
          ((u16*)Cv)[(long)(gc >> 10) * 16777216 + (long)gr * 1024 + (gc & 1023)]
              = f2bf(v + bval);
        } else if (MODE == 1) {
          ((u16*)Cv)[bz * BATCH_SC + (long)(mt * (mt + 1) / 2 + nt) * 16384 + rr * 128 + cc]
              = f2bf(v * scale);
        } else if (MODE == 2) {
          ((u16*)Cv)[(long)bz * cbst + (long)gr * ldc + gc] = f2bf(v);
        } else if (MODE == 3) {
          ((u16*)Cv)[(long)gr * ldc + gc] = f2bf(gelu_f(v + bias[gc]));
        }
      }
    }
  }
}

// =====================================================================
// gemm256_p8_ffn2: 8-phase counted-vmcnt 256x256 pipeline (T1-T5), FFN2.
// PASS 0: f32 Cv = acc                 (fallback K-half 0)
// PASS 1: f32 Cv += acc + bias + resid (fallback K-half 1)
// PASS 2: bf16 Cv = acc + bias + resid (big-ws single pass, K=4096)
// =====================================================================
template<int PASS>
__global__ __launch_bounds__(512, 2)
void gemm256_p8_ffn2(const u16* __restrict__ A, int lda,
                     const u16* __restrict__ Bt, int ldb,
                     void* __restrict__ Cv, int ldc,
                     const float* __restrict__ bias,
                     const u16* __restrict__ resid,
                     int K, int NNT)
{
  __shared__ char smem[131072];
  const int tid  = threadIdx.x;
  const int lane = tid & 63;
  const int wv   = tid >> 6;
  const int wm   = wv >> 2, wn = wv & 3;
  const int lrow = lane & 15;
  const int kgrp = lane >> 4;

  const int nwg = gridDim.x;
  const int q0 = nwg >> 3, r = nwg & 7, xc = blockIdx.x & 7, pos = blockIdx.x >> 3;
  const int s = (xc < r ? xc * (q0 + 1) : r * (q0 + 1) + (xc - r) * q0) + pos;
  const int mt = s / NNT, nt = s % NNT;   // M-major: neighbors share A panel
  const int m0 = mt * 256, n0 = nt * 256;

  auto stageA = [&](int ktile, int dslot, int h) {
    int k0 = ktile << 6; const int kmax = K - 64; if (k0 > kmax) k0 = kmax;
#pragma unroll
    for (int j = 0; j < 2; ++j) {
      const int o = j * 8192 + tid * 16;
      const int l = swz(o);
      gload_lds16(A + (long)(m0 + h * 128 + (l >> 7)) * lda + k0 + ((l & 127) >> 1),
                  smem + dslot * 65536 + h * 16384 + o);
    }
  };
  auto stageB = [&](int ktile, int dslot, int h) {
    int k0 = ktile << 6; const int kmax = K - 64; if (k0 > kmax) k0 = kmax;
#pragma unroll
    for (int j = 0; j < 2; ++j) {
      const int o = j * 8192 + tid * 16;
      const int l = swz(o);
      gload_lds16(Bt + (long)(n0 + h * 128 + (l >> 7)) * ldb + k0 + ((l & 127) >> 1),
                  smem + dslot * 65536 + 32768 + h * 16384 + o);
    }
  };
  auto rdfrag = [&](int bofs, int row, int ks) -> bf16x8 {
    const int p = swz(row * 128 + ks * 64 + kgrp * 16);
    return *(const bf16x8*)(smem + bofs + p);
  };

  f32x4 acc[8][4];
#pragma unroll
  for (int mi = 0; mi < 8; ++mi)
#pragma unroll
    for (int ni = 0; ni < 4; ++ni)
#pragma unroll
      for (int e = 0; e < 4; ++e) acc[mi][ni][e] = 0.f;

  stageA(0, 0, 0); stageA(0, 0, 1); stageB(0, 0, 0); stageB(0, 0, 1);
  stageB(1, 1, 0); stageB(1, 1, 1);
  asm volatile("s_waitcnt vmcnt(4)" ::: "memory");
  __builtin_amdgcn_s_barrier();

  const int NI = K >> 7;
  bf16x8 bfrag[4][2], afrag[2][2];
  for (int i = 0; i < NI; ++i) {
    const int kp = 2 * i;
#pragma unroll
    for (int d = 0; d < 2; ++d) {
#pragma unroll
      for (int mq = 0; mq < 4; ++mq) {
        const int ph = d * 4 + mq;
        if (mq == 0) {
#pragma unroll
          for (int ni = 0; ni < 4; ++ni)
#pragma unroll
            for (int ks = 0; ks < 2; ++ks)
              bfrag[ni][ks] = rdfrag(d * 65536 + 32768, wn * 64 + ni * 16 + lrow, ks);
        }
#pragma unroll
        for (int mi2 = 0; mi2 < 2; ++mi2)
#pragma unroll
          for (int ks = 0; ks < 2; ++ks)
            afrag[mi2][ks] = rdfrag(d * 65536, wm * 128 + (2 * mq + mi2) * 16 + lrow, ks);
        switch (ph) {
          case 0: stageA(kp + 1, 1, 0); break;
          case 1: stageA(kp + 1, 1, 1); break;
          case 2: stageB(kp + 2, 0, 0); break;
          case 3: stageB(kp + 2, 0, 1); break;
          case 4: stageA(kp + 2, 0, 0); break;
          case 5: stageA(kp + 2, 0, 1); break;
          case 6: stageB(kp + 3, 1, 0); break;
          case 7: stageB(kp + 3, 1, 1); break;
        }
        __builtin_amdgcn_s_barrier();
        asm volatile("s_waitcnt lgkmcnt(0)" ::: "memory");
        __builtin_amdgcn_s_setprio(1);
#pragma unroll
        for (int mi2 = 0; mi2 < 2; ++mi2)
#pragma unroll
          for (int ni = 0; ni < 4; ++ni)
#pragma unroll
            for (int ks = 0; ks < 2; ++ks)
              acc[2 * mq + mi2][ni] = __builtin_amdgcn_mfma_f32_16x16x32_bf16(
                  afrag[mi2][ks], bfrag[ni][ks], acc[2 * mq + mi2][ni], 0, 0, 0);
        __builtin_amdgcn_s_setprio(0);
        if (mq == 3) asm volatile("s_waitcnt vmcnt(4)" ::: "memory");
        __builtin_amdgcn_s_barrier();
      }
    }
  }

#pragma unroll
  for (int mi = 0; mi < 8; ++mi) {
#pragma unroll
    for (int ni = 0; ni < 4; ++ni) {
      const int gc = n0 + wn * 64 + ni * 16 + lrow;
#pragma unroll
      for (int e = 0; e < 4; ++e) {
        const int gr = m0 + wm * 128 + mi * 16 + kgrp * 4 + e;
        if (PASS == 0) {
          ((float*)Cv)[(long)gr * ldc + gc] = acc[mi][ni][e];
        } else if (PASS == 1) {
          float* o = &((float*)Cv)[(long)gr * ldc + gc];
          *o = *o + acc[mi][ni][e] + bias[gc] + bf2f(resid[(long)gr * 1024 + gc]);
        } else {
          ((u16*)Cv)[(long)gr * ldc + gc]
              = f2bf(acc[mi][ni][e] + bias[gc] + bf2f(resid[(long)gr * 1024 + gc]));
        }
      }
    }
  }
}

// ---------- all weight transposes in ONE launch: f32 [R][C] -> bf16 [C][R] ----------
__global__ __launch_bounds__(256)
void prep_weights(const float* __restrict__ Wq, const float* __restrict__ Wk,
                  const float* __restrict__ Wv, const float* __restrict__ W1,
                  const float* __restrict__ W2,
                  u16* __restrict__ wqkvT, u16* __restrict__ w1T, u16* __restrict__ w2T)
{
  const int idx = blockIdx.x;
  const float* in; u16* out; int R, C, cx0, ry0;
  if (idx < 3072) {
    in = (idx < 1024) ? Wq : (idx < 2048 ? Wk : Wv);
    out = wqkvT + (long)(idx >> 10) * 1048576;
    const int i = idx & 1023; cx0 = (i & 31) * 32; ry0 = (i >> 5) * 32; R = 1024; C = 1024;
  } else if (idx < 7168) {
    const int i = idx - 3072; in = W1; out = w1T; R = 1024; C = 4096;
    cx0 = (i & 127) * 32; ry0 = (i >> 7) * 32;
  } else {
    const int i = idx - 7168; in = W2; out = w2T; R = 4096; C = 1024;
    cx0 = (i & 31) * 32; ry0 = (i >> 5) * 32;
  }
  __shared__ float t[32][33];
  const int tx = threadIdx.x & 31, ty = threadIdx.x >> 5;
#pragma unroll
  for (int i = 0; i < 32; i += 8)
    t[ty + i][tx] = in[(long)(ry0 + ty + i) * C + (cx0 + tx)];
  __syncthreads();
#pragma unroll
  for (int i = 0; i < 32; i += 8)
    out[(long)(cx0 + ty + i) * R + (ry0 + tx)] = f2bf(t[tx][ty + i]);
}

// ---------- transpose bf16 [R][C] -> bf16 [C][R] (v^T), batched ----------
__global__ __launch_bounds__(256)
void transpose_v(const u16* __restrict__ inv, u16* __restrict__ out,
                 int R, int C, long ibst, long obst)
{
  __shared__ float t[32][33];
  const int bz = blockIdx.z;
  const int c0 = blockIdx.x * 32, r0 = blockIdx.y * 32;
  const int tx = threadIdx.x & 31, ty = threadIdx.x >> 5;
#pragma unroll
  for (int i = 0; i < 32; i += 8) {
    const long idx = (long)bz * ibst + (long)(r0 + ty + i) * C + (c0 + tx);
    t[ty + i][tx] = bf2f(inv[idx]);
  }
  __syncthreads();
#pragma unroll
  for (int i = 0; i < 32; i += 8)
    out[(long)bz * obst + (long)(c0 + ty + i) * R + (r0 + tx)] = f2bf(t[tx][ty + i]);
}

// ---------- f32 -> bf16 convert ----------
__global__ __launch_bounds__(256)
void cvt_f32_to_bf16(const float* __restrict__ in, u16* __restrict__ out, long n)
{
  const long idx = ((long)blockIdx.x * 256 + threadIdx.x) * 4;
  if (idx >= n) return;
  const float4 v = *(const float4*)(in + idx);
  ushort4 o;
  o.x = f2bf(v.x); o.y = f2bf(v.y); o.z = f2bf(v.z); o.w = f2bf(v.w);
  *(ushort4*)(out + idx) = o;
}

// ---------- causal row softmax on packed bf16 tiles, in place (16B vec) ----------
__global__ __launch_bounds__(256)
void softmax_packed(u16* __restrict__ sc)
{
  const int rowid = blockIdx.x;            // b*2048 + i
  const int b = rowid >> 11, i = rowid & 2047;
  const int mtt = i >> 7, rr = i & 127;
  u16* base = sc + (long)b * BATCH_SC + (long)(mtt * (mtt + 1) / 2) * 16384 + (long)rr * 128;
  const int t = threadIdx.x;
  const int lane = t & 63, wv = t >> 6;
  const int c   = t >> 4;
  const int off = (t & 15) * 8;
  const bool act = (c <= mtt);
  const int lim = (c < mtt) ? 8 : (c == mtt ? (rr - off + 1) : 0);
  u16* p = base + (long)c * 16384 + off;

  bf16x8 vv = {};
  if (act) vv = *(const bf16x8*)p;
  float vals[8];
  float m = -1e30f;
#pragma unroll
  for (int e = 0; e < 8; ++e) {
    vals[e] = (e < lim) ? bf2f((u16)vv[e]) : -1e30f;
    m = fmaxf(m, vals[e]);
  }
#pragma unroll
  for (int o = 1; o < 64; o <<= 1) m = fmaxf(m, __shfl_xor(m, o));
  __shared__ float rm[4], rsm[4];
  if (lane == 0) rm[wv] = m;
  __syncthreads();
  m = fmaxf(fmaxf(rm[0], rm[1]), fmaxf(rm[2], rm[3]));
  float pv[8];
  float ssum = 0.f;
#pragma unroll
  for (int e = 0; e < 8; ++e) { pv[e] = __expf(vals[e] - m); ssum += pv[e]; }
#pragma unroll
  for (int o = 1; o < 64; o <<= 1) ssum += __shfl_xor(ssum, o);
  if (lane == 0) rsm[wv] = ssum;
  __syncthreads();
  ssum = rsm[0] + rsm[1] + rsm[2] + rsm[3];
  const float inv = 1.f / ssum;
  if (act) {
    bf16x8 o;
#pragma unroll
    for (int e = 0; e < 8; ++e) o[e] = (short)f2bf(pv[e] * inv);
    *(bf16x8*)p = o;
  }
}

// ---------- LayerNorm rows of 1024; INBF/OUTBF: bf16 vs f32 ----------
template<int INBF, int OUTBF>
__global__ __launch_bounds__(256)
void layernorm_k(const void* __restrict__ in, const float* __restrict__ gam,
                 const float* __restrict__ bet, void* __restrict__ outv)
{
  const long row = blockIdx.x;
  const int t = threadIdx.x;
  const int lane = t & 63, wv = t >> 6;
  float v0, v1, v2, v3;
  if (INBF) {
    const ushort4 u = ((const ushort4*)in)[row * 256 + t];
    v0 = bf2f(u.x); v1 = bf2f(u.y); v2 = bf2f(u.z); v3 = bf2f(u.w);
  } else {
    const float4 v = ((const float4*)in)[row * 256 + t];
    v0 = v.x; v1 = v.y; v2 = v.z; v3 = v.w;
  }
  float s = v0 + v1 + v2 + v3;
  float q = v0 * v0 + v1 * v1 + v2 * v2 + v3 * v3;
#pragma unroll
  for (int o = 1; o < 64; o <<= 1) { s += __shfl_xor(s, o); q += __shfl_xor(q, o); }
  __shared__ float rs[4], rq[4];
  if (lane == 0) { rs[wv] = s; rq[wv] = q; }
  __syncthreads();
  s = rs[0] + rs[1] + rs[2] + rs[3];
  q = rq[0] + rq[1] + rq[2] + rq[3];
  const float mean = s * (1.f / 1024.f);
  const float var  = q * (1.f / 1024.f) - mean * mean;
  const float rstd = rsqrtf(var + 1e-5f);
  const float4 g4 = ((const float4*)gam)[t];
  const float4 b4 = ((const float4*)bet)[t];
  const float o0 = (v0 - mean) * rstd * g4.x + b4.x;
  const float o1 = (v1 - mean) * rstd * g4.y + b4.y;
  const float o2 = (v2 - mean) * rstd * g4.z + b4.z;
  const float o3 = (v3 - mean) * rstd * g4.w + b4.w;
  if (OUTBF) {
    ushort4 o; o.x = f2bf(o0); o.y = f2bf(o1); o.z = f2bf(o2); o.w = f2bf(o3);
    ((ushort4*)outv)[row * 256 + t] = o;
  } else {
    ((float4*)outv)[row * 256 + t] = make_float4(o0, o1, o2, o3);
  }
}

// =====================================================================
extern "C" void kernel_launch(void* const* d_in, const int* in_sizes, int n_in,
                              void* d_out, int out_size, void* d_ws, size_t ws_size,
                              hipStream_t stream)
{
  const float* x   = (const float*)d_in[0];
  const float* Wq  = (const float*)d_in[1];
  const float* bq  = (const float*)d_in[2];
  const float* Wk  = (const float*)d_in[3];
  const float* bk  = (const float*)d_in[4];
  const float* Wv  = (const float*)d_in[5];
  const float* bv  = (const float*)d_in[6];
  const float* W1  = (const float*)d_in[7];
  const float* b1  = (const float*)d_in[8];
  const float* W2  = (const float*)d_in[9];
  const float* b2  = (const float*)d_in[10];
  const float* g1  = (const float*)d_in[11];
  const float* be1 = (const float*)d_in[12];
  const float* g2  = (const float*)d_in[13];
  const float* be2 = (const float*)d_in[14];

  // workspace layout (fallback peak 152 MiB; big path peak 214 MiB):
  //  [0,22M)     weights bf16 [N][K]: wqkvT(6M) | w1T(8M) | w2T(8M)
  //  [22,54M)    xb (x bf16) -> vt (v^T) -> ffn2out bf16 (big path)
  //  [54,86M)    q -> ln1
  //  [86,118M)   k -> pvout bf16 -> h region start
  //  [118,152M)  v -> sc (packed causal bf16, 35.7 MB)
  //  h: big path [86,214M) full 128 MB; fallback [86,150M) 64 MB half
  char* ws = (char*)d_ws;
  u16*   wqkvT = (u16*)(ws);
  u16*   w1T   = (u16*)(ws + 6291456);
  u16*   w2T   = (u16*)(ws + 14680064);
  u16*   xb    = (u16*)(ws + 23068672);
  u16*   vt    = xb;
  u16*   f2out = xb;                              // FFN2 bf16 out (big path), over vt
  u16*   qkv   = (u16*)(ws + 56623104);
  u16*   qbuf  = qkv;
  u16*   kbuf  = qkv + 16777216;
  u16*   vbuf  = qkv + 33554432;
  u16*   ln1   = qbuf;
  u16*   pvout = kbuf;
  u16*   sc    = (u16*)(ws + 123731968);
  u16*   hbuf  = kbuf;                            // h region starts at 86M
  const bool big = (ws_size >= 224395264ULL);

  const dim3 B256(256);

  // 1. x -> bf16
  cvt_f32_to_bf16<<<dim3(16384), B256, 0, stream>>>(x, xb, 16777216L);

  // 2. all weight transposes, one launch (11264 tiles)
  prep_weights<<<dim3(11264), B256, 0, stream>>>(Wq, Wk, Wv, W1, W2, wqkvT, w1T, w2T);

  // 3. fused QKV: M=16384, N=3072, K=1024 (grid 24x128) — now swizzled
  gemm_bt<0><<<dim3(24, 128), B256, 0, stream>>>(xb, 1024, 0, wqkvT, 1024, 0, qkv, 1024, 0,
                                                 bq, bk, bv, 1024, 1.f);

  // 4. v -> v^T per batch, over dead xb
  transpose_v<<<dim3(32, 64, 8), B256, 0, stream>>>(vbuf, vt, 2048, 1024, 2097152, 2097152);

  // 5. scores = q@k^T/32 -> packed causal bf16 — swizzled
  gemm_bt<1><<<dim3(16, 16, 8), B256, 0, stream>>>(qbuf, 1024, 2097152, kbuf, 1024, 2097152,
                                                   sc, 0, 0, nullptr, nullptr, nullptr,
                                                   1024, 0.03125f);

  // 6. row softmax in place
  softmax_packed<<<dim3(16384), B256, 0, stream>>>(sc);

  // 7. attn = probs @ v -> bf16 pvout (block-causal Keff) — swizzled
  gemm_bt<2><<<dim3(8, 16, 8), B256, 0, stream>>>(sc, 0, 0, vt, 2048, 2097152,
                                                  pvout, 1024, 2097152, nullptr, nullptr,
                                                  nullptr, 0, 1.f);

  // 8. LN1: pvout bf16 -> ln1 bf16
  layernorm_k<1, 1><<<dim3(16384), B256, 0, stream>>>(pvout, g1, be1, ln1);

  if (big) {
    // 9a. FFN1 single launch (swizzled; R9: 172 us, conflicts 0)
    gemm_bt<3><<<dim3(32, 128), B256, 0, stream>>>(ln1, 1024, 0, w1T, 1024, 0, hbuf, 4096, 0,
                                                   b1, nullptr, nullptr, 1024, 1.f);
    // 10a. FFN2 single p8: M=16384, N=1024, K=4096, grid 256, bf16 out (vt dead)
    gemm256_p8_ffn2<2><<<dim3(256), dim3(512), 0, stream>>>(hbuf, 4096, w2T, 4096,
                                                            f2out, 1024, b2, ln1, 4096, 4);
    // 11a. LN2: f2out bf16 -> d_out f32
    layernorm_k<1, 0><<<dim3(16384), B256, 0, stream>>>(f2out, g2, be2, d_out);
  } else {
    // 9b/10b. fallback: N_ff split in 2 halves of 2048 (h 64 MB reused)
    for (int j = 0; j < 2; ++j) {
      const u16* w1h = w1T + (long)j * 2048 * 1024;
      gemm_bt<3><<<dim3(16, 128), B256, 0, stream>>>(ln1, 1024, 0, w1h, 1024, 0, hbuf, 2048, 0,
                                                     b1 + j * 2048, nullptr, nullptr,
                                                     1024, 1.f);
      if (j == 0)
        gemm256_p8_ffn2<0><<<dim3(256), dim3(512), 0, stream>>>(hbuf, 2048, w2T, 4096,
                                                                d_out, 1024,
                                                                nullptr, nullptr, 2048, 4);
      else
        gemm256_p8_ffn2<1><<<dim3(256), dim3(512), 0, stream>>>(hbuf, 2048, w2T + 2048, 4096,
                                                                d_out, 1024,
                                                                b2, ln1, 2048, 4);
    }
    // 11b. LN2 in place on d_out (f32)
    layernorm_k<0, 0><<<dim3(16384), B256, 0, stream>>>(d_out, g2, be2, d_out);
  }
}